// Round 1
// baseline (3005.051 us; speedup 1.0000x reference)
//
#include <hip/hip_runtime.h>

#define N_TOK 8192
#define IN_DIM 512
#define HID 256
#define OUT_DIM 512

// ---------- bf16 helpers (manual, dependency-free) ----------
__device__ inline unsigned f2bf(float x) {
    union { float f; unsigned u; } c; c.f = x;
    unsigned u = c.u;
    u += 0x7fffu + ((u >> 16) & 1u);   // round-to-nearest-even
    return u >> 16;                    // bf16 in low 16 bits
}
__device__ inline float bflo(unsigned u) {  // low bf16 of packed pair -> f32
    union { unsigned i; float f; } c; c.i = u << 16; return c.f;
}
__device__ inline float bfhi(unsigned u) {  // high bf16 of packed pair -> f32
    union { unsigned i; float f; } c; c.i = u & 0xffff0000u; return c.f;
}

// ---------- tiled fp32 GEMM:  C[M x NC] = A[M x K] @ B[NC x K]^T + bias ----------
// BM=32 rows, BNC=64 cols, BK=128 per block; 256 threads.
// BF16OUT: round result to bf16 (for q/k/v), else fp32 out.
template <bool BF16OUT>
__global__ __launch_bounds__(256)
void gemm_nt(const float* __restrict__ A, const float* __restrict__ B,
             const float* __restrict__ bias, void* __restrict__ Cout,
             int M, int K, int NC) {
    __shared__ float As[32][132];   // +4 pad: breaks power-of-2 bank stride
    __shared__ float Bs[64][132];

    const int t = threadIdx.x;
    const int row0 = blockIdx.x * 32;
    const int col0 = blockIdx.y * 64;
    const int r  = t & 31;   // output row within tile
    const int cg = t >> 5;   // output col group (8 cols each)

    float acc[8];
#pragma unroll
    for (int j = 0; j < 8; j++) acc[j] = 0.0f;

    for (int k0 = 0; k0 < K; k0 += 128) {
        __syncthreads();
        // stage A tile: 32x128 floats = 1024 float4, 4 per thread (coalesced)
#pragma unroll
        for (int i = 0; i < 4; i++) {
            int slot = t + 256 * i;
            int ar = slot >> 5, ac = slot & 31;
            *(float4*)&As[ar][ac * 4] =
                *(const float4*)&A[(size_t)(row0 + ar) * K + k0 + ac * 4];
        }
        // stage B tile: 64x128 floats = 2048 float4, 8 per thread
#pragma unroll
        for (int i = 0; i < 8; i++) {
            int slot = t + 256 * i;
            int br = slot >> 5, bc = slot & 31;
            *(float4*)&Bs[br][bc * 4] =
                *(const float4*)&B[(size_t)(col0 + br) * K + k0 + bc * 4];
        }
        __syncthreads();

        for (int kk = 0; kk < 128; kk += 4) {
            float4 a4 = *(const float4*)&As[r][kk];
#pragma unroll
            for (int j = 0; j < 8; j++) {
                float4 b4 = *(const float4*)&Bs[cg * 8 + j][kk];
                acc[j] += a4.x * b4.x + a4.y * b4.y + a4.z * b4.z + a4.w * b4.w;
            }
        }
    }

    const int col = col0 + cg * 8;
    float vals[8];
#pragma unroll
    for (int j = 0; j < 8; j++) vals[j] = acc[j] + bias[col + j];

    if (BF16OUT) {
        unsigned p0 = f2bf(vals[0]) | (f2bf(vals[1]) << 16);
        unsigned p1 = f2bf(vals[2]) | (f2bf(vals[3]) << 16);
        unsigned p2 = f2bf(vals[4]) | (f2bf(vals[5]) << 16);
        unsigned p3 = f2bf(vals[6]) | (f2bf(vals[7]) << 16);
        uint4 pk = make_uint4(p0, p1, p2, p3);
        *(uint4*)((unsigned short*)Cout + (size_t)(row0 + r) * NC + col) = pk;
    } else {
        float* C = (float*)Cout;
        *(float4*)&C[(size_t)(row0 + r) * NC + col] =
            make_float4(vals[0], vals[1], vals[2], vals[3]);
        *(float4*)&C[(size_t)(row0 + r) * NC + col + 4] =
            make_float4(vals[4], vals[5], vals[6], vals[7]);
    }
}

// ---------- flash attention: O = softmax(q k^T) v ----------
// 32 query rows per block, 32-key tiles, D=256. q/k/v are bf16 in workspace.
// 256 threads: thread = (row r = t>>3, colgroup cg = t&7 owning 32 of 256 O-cols).
__global__ __launch_bounds__(256)
void flash_attn(const unsigned short* __restrict__ qb,
                const unsigned short* __restrict__ kb,
                const unsigned short* __restrict__ vb,
                float* __restrict__ o) {
    const int D = 256;
    __shared__ unsigned short qs[32][264];  // bf16, +8 pad
    __shared__ unsigned short ks[32][264];
    __shared__ unsigned short vs[32][264];
    __shared__ float Ss[32][33];

    const int t = threadIdx.x;
    const int m0 = blockIdx.x * 32;

    // stage q tile: 32x256 bf16 = 1024 uint4 (8 bf16 each), 4 per thread
#pragma unroll
    for (int i = 0; i < 4; i++) {
        int slot = t + 256 * i;
        int rr = slot >> 5, cc = slot & 31;
        *(uint4*)&qs[rr][cc * 8] = *(const uint4*)&qb[(size_t)(m0 + rr) * D + cc * 8];
    }

    const int r  = t >> 3;  // query row (0..31)
    const int cg = t & 7;   // O column group: cols cg*32 .. cg*32+31
    float acc[32];
#pragma unroll
    for (int i = 0; i < 32; i++) acc[i] = 0.0f;
    float mrow = -1e30f, lrow = 0.0f;

    for (int n0 = 0; n0 < N_TOK; n0 += 32) {
        __syncthreads();
#pragma unroll
        for (int i = 0; i < 4; i++) {
            int slot = t + 256 * i;
            int rr = slot >> 5, cc = slot & 31;
            *(uint4*)&ks[rr][cc * 8] = *(const uint4*)&kb[(size_t)(n0 + rr) * D + cc * 8];
            *(uint4*)&vs[rr][cc * 8] = *(const uint4*)&vb[(size_t)(n0 + rr) * D + cc * 8];
        }
        __syncthreads();

        // S tile: thread computes S[rs][ns..ns+3], dot length 256
        {
            const int rs = t >> 3;
            const int ns = (t & 7) * 4;
            float s0 = 0.f, s1 = 0.f, s2 = 0.f, s3 = 0.f;
            for (int kk = 0; kk < D; kk += 4) {
                uint2 aq = *(const uint2*)&qs[rs][kk];
                float a0 = bflo(aq.x), a1 = bfhi(aq.x);
                float a2 = bflo(aq.y), a3 = bfhi(aq.y);
                uint2 b0 = *(const uint2*)&ks[ns + 0][kk];
                uint2 b1 = *(const uint2*)&ks[ns + 1][kk];
                uint2 b2 = *(const uint2*)&ks[ns + 2][kk];
                uint2 b3 = *(const uint2*)&ks[ns + 3][kk];
                s0 += a0 * bflo(b0.x) + a1 * bfhi(b0.x) + a2 * bflo(b0.y) + a3 * bfhi(b0.y);
                s1 += a0 * bflo(b1.x) + a1 * bfhi(b1.x) + a2 * bflo(b1.y) + a3 * bfhi(b1.y);
                s2 += a0 * bflo(b2.x) + a1 * bfhi(b2.x) + a2 * bflo(b2.y) + a3 * bfhi(b2.y);
                s3 += a0 * bflo(b3.x) + a1 * bfhi(b3.x) + a2 * bflo(b3.y) + a3 * bfhi(b3.y);
            }
            Ss[rs][ns + 0] = s0;
            Ss[rs][ns + 1] = s1;
            Ss[rs][ns + 2] = s2;
            Ss[rs][ns + 3] = s3;
        }
        __syncthreads();

        // online softmax + PV accumulate (each of the 8 threads sharing a row
        // computes m/l redundantly from identical LDS data -> consistent)
        float mt = -1e30f;
#pragma unroll
        for (int n = 0; n < 32; n++) mt = fmaxf(mt, Ss[r][n]);
        float mnew  = fmaxf(mrow, mt);
        float alpha = __expf(mrow - mnew);
        lrow *= alpha;
#pragma unroll
        for (int i = 0; i < 32; i++) acc[i] *= alpha;

        for (int n = 0; n < 32; n++) {
            float p = __expf(Ss[r][n] - mnew);
            lrow += p;
#pragma unroll
            for (int j = 0; j < 32; j += 4) {
                uint2 vv = *(const uint2*)&vs[n][cg * 32 + j];
                acc[j + 0] += p * bflo(vv.x);
                acc[j + 1] += p * bfhi(vv.x);
                acc[j + 2] += p * bflo(vv.y);
                acc[j + 3] += p * bfhi(vv.y);
            }
        }
        mrow = mnew;
    }

    const float inv = 1.0f / lrow;
#pragma unroll
    for (int j = 0; j < 32; j += 4) {
        *(float4*)&o[(size_t)(m0 + r) * D + cg * 32 + j] =
            make_float4(acc[j] * inv, acc[j + 1] * inv, acc[j + 2] * inv, acc[j + 3] * inv);
    }
}

extern "C" void kernel_launch(void* const* d_in, const int* in_sizes, int n_in,
                              void* d_out, int out_size, void* d_ws, size_t ws_size,
                              hipStream_t stream) {
    const float* O0    = (const float*)d_in[0];
    const float* W_w   = (const float*)d_in[1];
    const float* W_b   = (const float*)d_in[2];
    const float* U_w   = (const float*)d_in[3];
    const float* U_b   = (const float*)d_in[4];
    const float* H_w   = (const float*)d_in[5];
    const float* H_b   = (const float*)d_in[6];
    const float* fc0_w = (const float*)d_in[7];
    const float* fc0_b = (const float*)d_in[8];
    float* out = (float*)d_out;

    // workspace layout: q,k,v as bf16 (4 MB each), attn out fp32 (8 MB) = 20 MB
    unsigned short* qb = (unsigned short*)d_ws;
    unsigned short* kb = qb + (size_t)N_TOK * HID;
    unsigned short* vb = kb + (size_t)N_TOK * HID;
    float* attn = (float*)(vb + (size_t)N_TOK * HID);

    dim3 blk(256);
    // projections: [8192,512] @ [256,512]^T + b -> bf16 q/k/v
    gemm_nt<true><<<dim3(N_TOK / 32, HID / 64), blk, 0, stream>>>(
        O0, W_w, W_b, qb, N_TOK, IN_DIM, HID);
    gemm_nt<true><<<dim3(N_TOK / 32, HID / 64), blk, 0, stream>>>(
        O0, U_w, U_b, kb, N_TOK, IN_DIM, HID);
    gemm_nt<true><<<dim3(N_TOK / 32, HID / 64), blk, 0, stream>>>(
        O0, H_w, H_b, vb, N_TOK, IN_DIM, HID);

    // flash attention -> attn fp32 [8192, 256]
    flash_attn<<<dim3(N_TOK / 32), blk, 0, stream>>>(qb, kb, vb, attn);

    // fc0: [8192,256] @ [512,256]^T + b -> out fp32 [8192, 512]
    gemm_nt<false><<<dim3(N_TOK / 32, OUT_DIM / 64), blk, 0, stream>>>(
        attn, fc0_w, fc0_b, out, N_TOK, HID, OUT_DIM);
}

// Round 2
// 516.967 us; speedup vs baseline: 5.8128x; 5.8128x over previous
//
#include <hip/hip_runtime.h>

#define N_TOK 8192
#define IN_DIM 512
#define HID 256
#define OUT_DIM 512

typedef _Float16 v8h __attribute__((ext_vector_type(8)));
typedef float v4f __attribute__((ext_vector_type(4)));

// ---------- tiled fp32 GEMM:  C[M x NC] = A[M x K] @ B[NC x K]^T + bias ----------
// BM=32 rows, BNC=64 cols, BK=128 per block; 256 threads.
// F16OUT: round result to fp16 (for q/k/v), else fp32 out.
template <bool F16OUT>
__global__ __launch_bounds__(256)
void gemm_nt(const float* __restrict__ A, const float* __restrict__ B,
             const float* __restrict__ bias, void* __restrict__ Cout,
             int M, int K, int NC) {
    __shared__ float As[32][132];
    __shared__ float Bs[64][132];

    const int t = threadIdx.x;
    const int row0 = blockIdx.x * 32;
    const int col0 = blockIdx.y * 64;
    const int r  = t & 31;
    const int cg = t >> 5;

    float acc[8];
#pragma unroll
    for (int j = 0; j < 8; j++) acc[j] = 0.0f;

    for (int k0 = 0; k0 < K; k0 += 128) {
        __syncthreads();
#pragma unroll
        for (int i = 0; i < 4; i++) {
            int slot = t + 256 * i;
            int ar = slot >> 5, ac = slot & 31;
            *(float4*)&As[ar][ac * 4] =
                *(const float4*)&A[(size_t)(row0 + ar) * K + k0 + ac * 4];
        }
#pragma unroll
        for (int i = 0; i < 8; i++) {
            int slot = t + 256 * i;
            int br = slot >> 5, bc = slot & 31;
            *(float4*)&Bs[br][bc * 4] =
                *(const float4*)&B[(size_t)(col0 + br) * K + k0 + bc * 4];
        }
        __syncthreads();

        for (int kk = 0; kk < 128; kk += 4) {
            float4 a4 = *(const float4*)&As[r][kk];
#pragma unroll
            for (int j = 0; j < 8; j++) {
                float4 b4 = *(const float4*)&Bs[cg * 8 + j][kk];
                acc[j] += a4.x * b4.x + a4.y * b4.y + a4.z * b4.z + a4.w * b4.w;
            }
        }
    }

    const int col = col0 + cg * 8;
    float vals[8];
#pragma unroll
    for (int j = 0; j < 8; j++) vals[j] = acc[j] + bias[col + j];

    if (F16OUT) {
        union { _Float16 h[8]; uint4 v; } pk;
#pragma unroll
        for (int j = 0; j < 8; j++) pk.h[j] = (_Float16)vals[j];
        *(uint4*)((_Float16*)Cout + (size_t)(row0 + r) * NC + col) = pk.v;
    } else {
        float* C = (float*)Cout;
        *(float4*)&C[(size_t)(row0 + r) * NC + col] =
            make_float4(vals[0], vals[1], vals[2], vals[3]);
        *(float4*)&C[(size_t)(row0 + r) * NC + col + 4] =
            make_float4(vals[4], vals[5], vals[6], vals[7]);
    }
}

// ---------- transpose: vb [8192][256] f16 -> vt [256][8192] f16 ----------
__global__ __launch_bounds__(256)
void transpose_v(const _Float16* __restrict__ vb, _Float16* __restrict__ vt) {
    __shared__ _Float16 tile[64][68];
    const int t = threadIdx.x;
    const int n0 = blockIdx.x * 64, d0 = blockIdx.y * 64;
#pragma unroll
    for (int i = 0; i < 4; i++) {
        int slot = t + 256 * i;
        int r = slot >> 4, c4 = slot & 15;
        *(uint2*)&tile[r][c4 * 4] =
            *(const uint2*)&vb[(size_t)(n0 + r) * HID + d0 + c4 * 4];
    }
    __syncthreads();
#pragma unroll
    for (int i = 0; i < 4; i++) {
        int slot = t + 256 * i;
        int dr = slot >> 4, c4 = slot & 15;
        union { _Float16 h[4]; uint2 v; } pk;
#pragma unroll
        for (int j = 0; j < 4; j++) pk.h[j] = tile[c4 * 4 + j][dr];
        *(uint2*)&vt[(size_t)(d0 + dr) * N_TOK + n0 + c4 * 4] = pk.v;
    }
}

// ---------- MFMA flash attention ----------
// Block: 256 thr = 4 waves x 32 Q-rows (BM=128). BN=32 keys/iter, D=256.
// grid = (64, P): x = row block, y = key partition. Partial (unnormalized
// O, m, l) written per partition; combined by combine_parts.
__global__ __launch_bounds__(256, 1)
void flash_mfma(const _Float16* __restrict__ qb, const _Float16* __restrict__ kb,
                const _Float16* __restrict__ vt,
                float* __restrict__ part0, float* __restrict__ part1,
                float* __restrict__ part2, float* __restrict__ part3,
                float* __restrict__ mbuf, float* __restrict__ lbuf,
                int keys_per_part) {
    __shared__ _Float16 Ks[32][264];     // K tile, pad 264: 2-way-free banks
    __shared__ _Float16 Vs[256][40];     // V^T tile, pad 40: 2-way-free banks
    __shared__ _Float16 Ps[4][32][40];   // per-wave P tile

    const int t = threadIdx.x;
    const int w = t >> 6;
    const int lane = t & 63;
    const int quad = lane >> 4;
    const int lm = lane & 15;
    const int p = blockIdx.y;
    const int m0 = blockIdx.x * 128 + w * 32;

    float* part = (p == 0) ? part0 : (p == 1) ? part1 : (p == 2) ? part2 : part3;

    // Q fragments for 2 rowsets x 8 k-chunks, held in registers
    v8h aq[2][8];
#pragma unroll
    for (int rs = 0; rs < 2; rs++)
#pragma unroll
        for (int c = 0; c < 8; c++)
            aq[rs][c] = *(const v8h*)&qb[(size_t)(m0 + rs * 16 + lm) * HID + c * 32 + quad * 8];

    v4f o[2][16];
    float mr[2][4], lr[2][4];
#pragma unroll
    for (int rs = 0; rs < 2; rs++) {
#pragma unroll
        for (int dt = 0; dt < 16; dt++) o[rs][dt] = (v4f){0.f, 0.f, 0.f, 0.f};
#pragma unroll
        for (int r = 0; r < 4; r++) { mr[rs][r] = -1e30f; lr[rs][r] = 0.f; }
    }

    const int n_start = p * keys_per_part;
    for (int n0 = n_start; n0 < n_start + keys_per_part; n0 += 32) {
        __syncthreads();
        // stage K tile [32][256] (1024 uint4, 4/thread) and V^T tile [256][32]
#pragma unroll
        for (int i = 0; i < 4; i++) {
            int slot = t + 256 * i;
            int kr = slot >> 5, kc = slot & 31;
            *(uint4*)&Ks[kr][kc * 8] =
                *(const uint4*)&kb[(size_t)(n0 + kr) * HID + kc * 8];
        }
#pragma unroll
        for (int i = 0; i < 4; i++) {
            int slot = t + 256 * i;
            int d = slot >> 2, c = slot & 3;
            *(uint4*)&Vs[d][c * 8] =
                *(const uint4*)&vt[(size_t)d * N_TOK + n0 + c * 8];
        }
        __syncthreads();

        // QK^T: S[32 rows][32 keys] per wave = 2 rowsets x 2 ntiles
        v4f s[2][2];
#pragma unroll
        for (int rs = 0; rs < 2; rs++)
#pragma unroll
            for (int nt = 0; nt < 2; nt++) s[rs][nt] = (v4f){0.f, 0.f, 0.f, 0.f};
#pragma unroll
        for (int c = 0; c < 8; c++) {
            v8h b0 = *(const v8h*)&Ks[lm][c * 32 + quad * 8];
            v8h b1 = *(const v8h*)&Ks[16 + lm][c * 32 + quad * 8];
            s[0][0] = __builtin_amdgcn_mfma_f32_16x16x32_f16(aq[0][c], b0, s[0][0], 0, 0, 0);
            s[0][1] = __builtin_amdgcn_mfma_f32_16x16x32_f16(aq[0][c], b1, s[0][1], 0, 0, 0);
            s[1][0] = __builtin_amdgcn_mfma_f32_16x16x32_f16(aq[1][c], b0, s[1][0], 0, 0, 0);
            s[1][1] = __builtin_amdgcn_mfma_f32_16x16x32_f16(aq[1][c], b1, s[1][1], 0, 0, 0);
        }

        // online softmax per rowset (rows = quad*4+r), P -> own LDS slice
#pragma unroll
        for (int rs = 0; rs < 2; rs++) {
            float al[4];
#pragma unroll
            for (int r = 0; r < 4; r++) {
                float tm = fmaxf(s[rs][0][r], s[rs][1][r]);
#pragma unroll
                for (int d = 1; d < 16; d <<= 1) tm = fmaxf(tm, __shfl_xor(tm, d));
                float mn = fmaxf(mr[rs][r], tm);
                float a = __expf(mr[rs][r] - mn);
                mr[rs][r] = mn;
                al[r] = a;
                float p0 = __expf(s[rs][0][r] - mn);
                float p1v = __expf(s[rs][1][r] - mn);
                float sm = p0 + p1v;
#pragma unroll
                for (int d = 1; d < 16; d <<= 1) sm += __shfl_xor(sm, d);
                lr[rs][r] = lr[rs][r] * a + sm;
                const int prow = rs * 16 + quad * 4 + r;
                Ps[w][prow][lm] = (_Float16)p0;
                Ps[w][prow][16 + lm] = (_Float16)p1v;
            }
#pragma unroll
            for (int dt = 0; dt < 16; dt++)
#pragma unroll
                for (int r = 0; r < 4; r++) o[rs][dt][r] *= al[r];
        }

        // PV: own-wave P slice, no barrier needed (compiler orders via lgkmcnt)
        v8h ap0 = *(const v8h*)&Ps[w][lm][quad * 8];
        v8h ap1 = *(const v8h*)&Ps[w][16 + lm][quad * 8];
#pragma unroll
        for (int dt = 0; dt < 16; dt++) {
            v8h bv = *(const v8h*)&Vs[dt * 16 + lm][quad * 8];
            o[0][dt] = __builtin_amdgcn_mfma_f32_16x16x32_f16(ap0, bv, o[0][dt], 0, 0, 0);
            o[1][dt] = __builtin_amdgcn_mfma_f32_16x16x32_f16(ap1, bv, o[1][dt], 0, 0, 0);
        }
    }

    // store unnormalized partial O + m,l
#pragma unroll
    for (int rs = 0; rs < 2; rs++) {
#pragma unroll
        for (int dt = 0; dt < 16; dt++)
#pragma unroll
            for (int r = 0; r < 4; r++)
                part[(size_t)(m0 + rs * 16 + quad * 4 + r) * HID + dt * 16 + lm] = o[rs][dt][r];
        if (lm == 0) {
#pragma unroll
            for (int r = 0; r < 4; r++) {
                int row = m0 + rs * 16 + quad * 4 + r;
                mbuf[p * N_TOK + row] = mr[rs][r];
                lbuf[p * N_TOK + row] = lr[rs][r];
            }
        }
    }
}

// ---------- combine key-split partials ----------
__global__ __launch_bounds__(256)
void combine_parts(float* __restrict__ attn,
                   const float* __restrict__ q0, const float* __restrict__ q1,
                   const float* __restrict__ q2, const float* __restrict__ q3,
                   const float* __restrict__ mbuf, const float* __restrict__ lbuf,
                   int P) {
    const int gid = blockIdx.x * 256 + threadIdx.x;  // float4 index
    const int row = gid >> 6;
    const int c4 = (gid & 63) * 4;
    const float* parts[4] = {q0, q1, q2, q3};

    float M = -1e30f;
    for (int p = 0; p < P; p++) M = fmaxf(M, mbuf[p * N_TOK + row]);
    float denom = 0.f;
    float4 acc = make_float4(0.f, 0.f, 0.f, 0.f);
    for (int p = 0; p < P; p++) {
        float wgt = __expf(mbuf[p * N_TOK + row] - M);
        denom += wgt * lbuf[p * N_TOK + row];
        float4 v = *(const float4*)&parts[p][(size_t)row * HID + c4];
        acc.x += wgt * v.x; acc.y += wgt * v.y; acc.z += wgt * v.z; acc.w += wgt * v.w;
    }
    const float inv = 1.0f / denom;
    *(float4*)&attn[(size_t)row * HID + c4] =
        make_float4(acc.x * inv, acc.y * inv, acc.z * inv, acc.w * inv);
}

extern "C" void kernel_launch(void* const* d_in, const int* in_sizes, int n_in,
                              void* d_out, int out_size, void* d_ws, size_t ws_size,
                              hipStream_t stream) {
    const float* O0    = (const float*)d_in[0];
    const float* W_w   = (const float*)d_in[1];
    const float* W_b   = (const float*)d_in[2];
    const float* U_w   = (const float*)d_in[3];
    const float* U_b   = (const float*)d_in[4];
    const float* H_w   = (const float*)d_in[5];
    const float* H_b   = (const float*)d_in[6];
    const float* fc0_w = (const float*)d_in[7];
    const float* fc0_b = (const float*)d_in[8];
    float* out = (float*)d_out;

    // workspace layout (MB offsets):
    // 0: qb f16 (4)  4: kb f16 (4)  8: vb f16 (4)  12: vt f16 (4)
    // 16: mbuf/lbuf (0.25)  17: part2 (8)  25: part3 (8)   [P=4 only]
    // attn fp32 (8) aliases 0..8 (qb/kb dead after flash)
    char* ws = (char*)d_ws;
    _Float16* qb = (_Float16*)ws;
    _Float16* kb = (_Float16*)(ws + ((size_t)4 << 20));
    _Float16* vb = (_Float16*)(ws + ((size_t)8 << 20));
    _Float16* vt = (_Float16*)(ws + ((size_t)12 << 20));
    float* mbuf  = (float*)(ws + ((size_t)16 << 20));
    float* lbuf  = mbuf + 4 * N_TOK;
    float* part2 = (float*)(ws + ((size_t)17 << 20));
    float* part3 = (float*)(ws + ((size_t)25 << 20));
    float* attn  = (float*)ws;
    float* part0 = (float*)d_out;                // d_out holds 2 partials (16 MB)
    float* part1 = part0 + (size_t)N_TOK * HID;

    const int P = (ws_size >= ((size_t)34 << 20)) ? 4 : 2;  // ws-size constant -> graph-safe
    if (P == 2) { part2 = part0; part3 = part1; }           // unused dummies
    const int kpp = N_TOK / P;

    dim3 blk(256);
    // projections: [8192,512] @ [256,512]^T + b -> f16
    gemm_nt<true><<<dim3(N_TOK / 32, HID / 64), blk, 0, stream>>>(
        O0, W_w, W_b, qb, N_TOK, IN_DIM, HID);
    gemm_nt<true><<<dim3(N_TOK / 32, HID / 64), blk, 0, stream>>>(
        O0, U_w, U_b, kb, N_TOK, IN_DIM, HID);
    gemm_nt<true><<<dim3(N_TOK / 32, HID / 64), blk, 0, stream>>>(
        O0, H_w, H_b, vb, N_TOK, IN_DIM, HID);

    transpose_v<<<dim3(N_TOK / 64, HID / 64), blk, 0, stream>>>(vb, vt);

    flash_mfma<<<dim3(N_TOK / 128, P), blk, 0, stream>>>(
        qb, kb, vt, part0, part1, part2, part3, mbuf, lbuf, kpp);

    combine_parts<<<dim3(N_TOK * HID / 4 / 256), blk, 0, stream>>>(
        attn, part0, part1, part2, part3, mbuf, lbuf, P);

    // fc0: [8192,256] @ [512,256]^T + b -> out fp32
    gemm_nt<false><<<dim3(N_TOK / 32, OUT_DIM / 64), blk, 0, stream>>>(
        attn, fc0_w, fc0_b, out, N_TOK, HID, OUT_DIM);
}

// Round 5
// 354.411 us; speedup vs baseline: 8.4790x; 1.4587x over previous
//
#include <hip/hip_runtime.h>

#define N_TOK 8192
#define IN_DIM 512
#define HID 256
#define OUT_DIM 512

typedef _Float16 v8h __attribute__((ext_vector_type(8)));
typedef float v4f __attribute__((ext_vector_type(4)));

// ---------- convert fp32 -> f16, 8 elems/thread ----------
__global__ __launch_bounds__(256)
void conv_f16(const float* __restrict__ in, _Float16* __restrict__ out) {
    const size_t i = ((size_t)blockIdx.x * 256 + threadIdx.x) * 8;
    float4 f0 = *(const float4*)&in[i];
    float4 f1 = *(const float4*)&in[i + 4];
    union { _Float16 h[8]; uint4 u; } pk;
    pk.h[0] = (_Float16)f0.x; pk.h[1] = (_Float16)f0.y;
    pk.h[2] = (_Float16)f0.z; pk.h[3] = (_Float16)f0.w;
    pk.h[4] = (_Float16)f1.x; pk.h[5] = (_Float16)f1.y;
    pk.h[6] = (_Float16)f1.z; pk.h[7] = (_Float16)f1.w;
    *(uint4*)&out[i] = pk.u;
}

// ---------- MFMA GEMM: C[8192 x NC] = Ah[8192 x K](f16) @ B[NC x K](f32)^T + bias ----------
// BM=128 (4 waves x 32 rows), BN=64, BK=64. B converted f32->f16 during staging.
// NOTE: LDS row stride must be a multiple of 8 f16 (16 B) for b128 access.
// NOTE: A tile = 128x64 f16 = 1024 uint4 chunks -> 4 iters of 256 threads
//       (round-3/4 NaN bug: only 2 iters staged half the tile).
template <bool OUTF32>
__global__ __launch_bounds__(256)
void mfma_gemm(const _Float16* __restrict__ Ah, const float* __restrict__ B,
               const float* __restrict__ bias, void* __restrict__ Cout,
               int K, int NC) {
    __shared__ _Float16 As[128][72];   // 144 B row stride = 9*16 (aligned)
    __shared__ _Float16 Bs[64][72];

    const int t = threadIdx.x;
    const int wv = t >> 6;
    const int lane = t & 63;
    const int quad = lane >> 4;
    const int lm = lane & 15;
    const int m0 = blockIdx.x * 128;
    const int n0 = blockIdx.y * 64;

    v4f acc[2][4];
#pragma unroll
    for (int rs = 0; rs < 2; rs++)
#pragma unroll
        for (int ct = 0; ct < 4; ct++) acc[rs][ct] = (v4f){0.f, 0.f, 0.f, 0.f};

    for (int k0 = 0; k0 < K; k0 += 64) {
        __syncthreads();
        // stage A: 128x64 f16 = 1024 uint4, 4/thread
#pragma unroll
        for (int i = 0; i < 4; i++) {
            int slot = t + 256 * i;
            int ar = slot >> 3, ac8 = slot & 7;
            *(uint4*)&As[ar][ac8 * 8] =
                *(const uint4*)&Ah[(size_t)(m0 + ar) * K + k0 + ac8 * 8];
        }
        // stage B: 64x64 f32 -> f16, 1024 float4 slots, 4/thread
#pragma unroll
        for (int i = 0; i < 4; i++) {
            int slot = t + 256 * i;
            int br = slot >> 4, bc4 = slot & 15;
            float4 f = *(const float4*)&B[(size_t)(n0 + br) * K + k0 + bc4 * 4];
            union { _Float16 h[4]; uint2 u; } pk;
            pk.h[0] = (_Float16)f.x; pk.h[1] = (_Float16)f.y;
            pk.h[2] = (_Float16)f.z; pk.h[3] = (_Float16)f.w;
            *(uint2*)&Bs[br][bc4 * 4] = pk.u;
        }
        __syncthreads();

#pragma unroll
        for (int kc = 0; kc < 2; kc++) {
            v8h a0 = *(const v8h*)&As[wv * 32 + lm][kc * 32 + quad * 8];
            v8h a1 = *(const v8h*)&As[wv * 32 + 16 + lm][kc * 32 + quad * 8];
            v8h b[4];
#pragma unroll
            for (int ct = 0; ct < 4; ct++)
                b[ct] = *(const v8h*)&Bs[ct * 16 + lm][kc * 32 + quad * 8];
#pragma unroll
            for (int ct = 0; ct < 4; ct++) {
                acc[0][ct] = __builtin_amdgcn_mfma_f32_16x16x32_f16(a0, b[ct], acc[0][ct], 0, 0, 0);
                acc[1][ct] = __builtin_amdgcn_mfma_f32_16x16x32_f16(a1, b[ct], acc[1][ct], 0, 0, 0);
            }
        }
    }

#pragma unroll
    for (int rs = 0; rs < 2; rs++)
#pragma unroll
        for (int ct = 0; ct < 4; ct++) {
            const int col = n0 + ct * 16 + lm;
            const float bv = bias[col];
#pragma unroll
            for (int r = 0; r < 4; r++) {
                const int row = m0 + wv * 32 + rs * 16 + quad * 4 + r;
                float val = acc[rs][ct][r] + bv;
                if (OUTF32) ((float*)Cout)[(size_t)row * NC + col] = val;
                else        ((_Float16*)Cout)[(size_t)row * NC + col] = (_Float16)val;
            }
        }
}

// ---------- transpose: vb [8192][256] f16 -> vt [256][8192] f16 ----------
__global__ __launch_bounds__(256)
void transpose_v(const _Float16* __restrict__ vb, _Float16* __restrict__ vt) {
    __shared__ _Float16 tile[64][68];
    const int t = threadIdx.x;
    const int n0 = blockIdx.x * 64, d0 = blockIdx.y * 64;
#pragma unroll
    for (int i = 0; i < 4; i++) {
        int slot = t + 256 * i;
        int r = slot >> 4, c4 = slot & 15;
        *(uint2*)&tile[r][c4 * 4] =
            *(const uint2*)&vb[(size_t)(n0 + r) * HID + d0 + c4 * 4];
    }
    __syncthreads();
#pragma unroll
    for (int i = 0; i < 4; i++) {
        int slot = t + 256 * i;
        int dr = slot >> 4, c4 = slot & 15;
        union { _Float16 h[4]; uint2 v; } pk;
#pragma unroll
        for (int j = 0; j < 4; j++) pk.h[j] = tile[c4 * 4 + j][dr];
        *(uint2*)&vt[(size_t)(d0 + dr) * N_TOK + n0 + c4 * 4] = pk.v;
    }
}

// ---------- MFMA flash attention, key-split ----------
// Block: 256 thr = 4 waves x 32 Q-rows (BM=128). BN=32 keys/iter, D=256.
// grid = (64, P). Partition p writes NORMALIZED partial (O/l, f16) + m, l.
__global__ __launch_bounds__(256, 2)
void flash_mfma(const _Float16* __restrict__ qb, const _Float16* __restrict__ kb,
                const _Float16* __restrict__ vt,
                _Float16* __restrict__ partA,   // parts 0..3 (d_out)
                _Float16* __restrict__ partB,   // parts 4..7 (ws, P=8 only)
                float* __restrict__ mbuf, float* __restrict__ lbuf,
                int keys_per_part) {
    __shared__ _Float16 Ks[32][264];     // 528 B = 33*16 (aligned)
    __shared__ _Float16 Vs[256][40];     // 80 B = 5*16 (aligned)
    __shared__ _Float16 Ps[4][32][40];

    const int t = threadIdx.x;
    const int w = t >> 6;
    const int lane = t & 63;
    const int quad = lane >> 4;
    const int lm = lane & 15;
    const int p = blockIdx.y;
    const int m0 = blockIdx.x * 128 + w * 32;

    _Float16* part = (p < 4) ? partA + (size_t)p * N_TOK * HID
                             : partB + (size_t)(p - 4) * N_TOK * HID;

    v8h aq[2][8];
#pragma unroll
    for (int rs = 0; rs < 2; rs++)
#pragma unroll
        for (int c = 0; c < 8; c++)
            aq[rs][c] = *(const v8h*)&qb[(size_t)(m0 + rs * 16 + lm) * HID + c * 32 + quad * 8];

    v4f o[2][16];
    float mr[2][4], lr[2][4];
#pragma unroll
    for (int rs = 0; rs < 2; rs++) {
#pragma unroll
        for (int dt = 0; dt < 16; dt++) o[rs][dt] = (v4f){0.f, 0.f, 0.f, 0.f};
#pragma unroll
        for (int r = 0; r < 4; r++) { mr[rs][r] = -1e30f; lr[rs][r] = 0.f; }
    }

    const int n_start = p * keys_per_part;
    for (int n0 = n_start; n0 < n_start + keys_per_part; n0 += 32) {
        __syncthreads();
#pragma unroll
        for (int i = 0; i < 4; i++) {
            int slot = t + 256 * i;
            int kr = slot >> 5, kc = slot & 31;
            *(uint4*)&Ks[kr][kc * 8] =
                *(const uint4*)&kb[(size_t)(n0 + kr) * HID + kc * 8];
        }
#pragma unroll
        for (int i = 0; i < 4; i++) {
            int slot = t + 256 * i;
            int d = slot >> 2, c = slot & 3;
            *(uint4*)&Vs[d][c * 8] =
                *(const uint4*)&vt[(size_t)d * N_TOK + n0 + c * 8];
        }
        __syncthreads();

        // QK^T
        v4f s[2][2];
#pragma unroll
        for (int rs = 0; rs < 2; rs++)
#pragma unroll
            for (int nt = 0; nt < 2; nt++) s[rs][nt] = (v4f){0.f, 0.f, 0.f, 0.f};
#pragma unroll
        for (int c = 0; c < 8; c++) {
            v8h b0 = *(const v8h*)&Ks[lm][c * 32 + quad * 8];
            v8h b1 = *(const v8h*)&Ks[16 + lm][c * 32 + quad * 8];
            s[0][0] = __builtin_amdgcn_mfma_f32_16x16x32_f16(aq[0][c], b0, s[0][0], 0, 0, 0);
            s[0][1] = __builtin_amdgcn_mfma_f32_16x16x32_f16(aq[0][c], b1, s[0][1], 0, 0, 0);
            s[1][0] = __builtin_amdgcn_mfma_f32_16x16x32_f16(aq[1][c], b0, s[1][0], 0, 0, 0);
            s[1][1] = __builtin_amdgcn_mfma_f32_16x16x32_f16(aq[1][c], b1, s[1][1], 0, 0, 0);
        }

        // online softmax
#pragma unroll
        for (int rs = 0; rs < 2; rs++) {
            float al[4];
#pragma unroll
            for (int r = 0; r < 4; r++) {
                float tm = fmaxf(s[rs][0][r], s[rs][1][r]);
#pragma unroll
                for (int d = 1; d < 16; d <<= 1) tm = fmaxf(tm, __shfl_xor(tm, d));
                float mn = fmaxf(mr[rs][r], tm);
                float a = __expf(mr[rs][r] - mn);
                mr[rs][r] = mn;
                al[r] = a;
                float p0 = __expf(s[rs][0][r] - mn);
                float p1v = __expf(s[rs][1][r] - mn);
                float sm = p0 + p1v;
#pragma unroll
                for (int d = 1; d < 16; d <<= 1) sm += __shfl_xor(sm, d);
                lr[rs][r] = lr[rs][r] * a + sm;
                const int prow = rs * 16 + quad * 4 + r;
                Ps[w][prow][lm] = (_Float16)p0;
                Ps[w][prow][16 + lm] = (_Float16)p1v;
            }
#pragma unroll
            for (int dt = 0; dt < 16; dt++)
#pragma unroll
                for (int r = 0; r < 4; r++) o[rs][dt][r] *= al[r];
        }

        // PV (own-wave P slice; in-wave LDS ordering via lgkmcnt)
        v8h ap0 = *(const v8h*)&Ps[w][lm][quad * 8];
        v8h ap1 = *(const v8h*)&Ps[w][16 + lm][quad * 8];
#pragma unroll
        for (int dt = 0; dt < 16; dt++) {
            v8h bv = *(const v8h*)&Vs[dt * 16 + lm][quad * 8];
            o[0][dt] = __builtin_amdgcn_mfma_f32_16x16x32_f16(ap0, bv, o[0][dt], 0, 0, 0);
            o[1][dt] = __builtin_amdgcn_mfma_f32_16x16x32_f16(ap1, bv, o[1][dt], 0, 0, 0);
        }
    }

    // store normalized partial (f16) + m, l
#pragma unroll
    for (int rs = 0; rs < 2; rs++) {
        float inv[4];
#pragma unroll
        for (int r = 0; r < 4; r++) inv[r] = 1.0f / lr[rs][r];
#pragma unroll
        for (int dt = 0; dt < 16; dt++)
#pragma unroll
            for (int r = 0; r < 4; r++)
                part[(size_t)(m0 + rs * 16 + quad * 4 + r) * HID + dt * 16 + lm] =
                    (_Float16)(o[rs][dt][r] * inv[r]);
        if (lm == 0) {
#pragma unroll
            for (int r = 0; r < 4; r++) {
                int row = m0 + rs * 16 + quad * 4 + r;
                mbuf[p * N_TOK + row] = mr[rs][r];
                lbuf[p * N_TOK + row] = lr[rs][r];
            }
        }
    }
}

// ---------- combine normalized partials -> attn f16 ----------
__global__ __launch_bounds__(256)
void combine_parts(_Float16* __restrict__ attn,
                   const _Float16* __restrict__ partA, const _Float16* __restrict__ partB,
                   const float* __restrict__ mbuf, const float* __restrict__ lbuf,
                   int P) {
    const int gid = blockIdx.x * 256 + threadIdx.x;  // 8-elem chunk
    const int row = gid >> 5;
    const int c8 = (gid & 31) * 8;

    float M = -1e30f;
    for (int p = 0; p < P; p++) M = fmaxf(M, mbuf[p * N_TOK + row]);
    float den = 0.f;
    float acc[8];
#pragma unroll
    for (int j = 0; j < 8; j++) acc[j] = 0.f;
    for (int p = 0; p < P; p++) {
        float wgt = lbuf[p * N_TOK + row] * __expf(mbuf[p * N_TOK + row] - M);
        den += wgt;
        const _Float16* base = (p < 4) ? partA + (size_t)p * N_TOK * HID
                                       : partB + (size_t)(p - 4) * N_TOK * HID;
        v8h y = *(const v8h*)&base[(size_t)row * HID + c8];
#pragma unroll
        for (int j = 0; j < 8; j++) acc[j] += wgt * (float)y[j];
    }
    const float inv = 1.0f / den;
    union { _Float16 h[8]; uint4 u; } pk;
#pragma unroll
    for (int j = 0; j < 8; j++) pk.h[j] = (_Float16)(acc[j] * inv);
    *(uint4*)&attn[(size_t)row * HID + c8] = pk.u;
}

extern "C" void kernel_launch(void* const* d_in, const int* in_sizes, int n_in,
                              void* d_out, int out_size, void* d_ws, size_t ws_size,
                              hipStream_t stream) {
    const float* O0    = (const float*)d_in[0];
    const float* W_w   = (const float*)d_in[1];
    const float* W_b   = (const float*)d_in[2];
    const float* U_w   = (const float*)d_in[3];
    const float* U_b   = (const float*)d_in[4];
    const float* H_w   = (const float*)d_in[5];
    const float* H_b   = (const float*)d_in[6];
    const float* fc0_w = (const float*)d_in[7];
    const float* fc0_b = (const float*)d_in[8];

    // ws layout (MB):  0-8 O0h (dead after projections -> vt at 0-4,
    // mbuf/lbuf at 4-4.5)   8-12 qb (-> attn after flash)   12-16 kb
    // 16-32 parts 4..7 f16 (P=8 only).  d_out: vb 0-4 -> parts 0..3 0-16 -> final.
    char* ws = (char*)d_ws;
    _Float16* O0h  = (_Float16*)ws;
    _Float16* qb   = (_Float16*)(ws + ((size_t)8 << 20));
    _Float16* kb   = (_Float16*)(ws + ((size_t)12 << 20));
    _Float16* vt   = (_Float16*)ws;
    float*    mbuf = (float*)(ws + ((size_t)4 << 20));
    float*    lbuf = (float*)(ws + ((size_t)4 << 20) + ((size_t)256 << 10));
    _Float16* partB = (_Float16*)(ws + ((size_t)16 << 20));
    _Float16* attn = qb;
    _Float16* vb    = (_Float16*)d_out;
    _Float16* partA = (_Float16*)d_out;

    const int P = (ws_size >= ((size_t)32 << 20)) ? 8 : 4;  // ws-size constant -> graph-safe
    const int kpp = N_TOK / P;

    dim3 blk(256);
    conv_f16<<<dim3(N_TOK * IN_DIM / 8 / 256), blk, 0, stream>>>(O0, O0h);

    mfma_gemm<false><<<dim3(N_TOK / 128, HID / 64), blk, 0, stream>>>(
        O0h, W_w, W_b, qb, IN_DIM, HID);
    mfma_gemm<false><<<dim3(N_TOK / 128, HID / 64), blk, 0, stream>>>(
        O0h, U_w, U_b, kb, IN_DIM, HID);
    mfma_gemm<false><<<dim3(N_TOK / 128, HID / 64), blk, 0, stream>>>(
        O0h, H_w, H_b, vb, IN_DIM, HID);

    transpose_v<<<dim3(N_TOK / 64, HID / 64), blk, 0, stream>>>(vb, vt);

    flash_mfma<<<dim3(N_TOK / 128, P), blk, 0, stream>>>(
        qb, kb, vt, partA, partB, mbuf, lbuf, kpp);

    combine_parts<<<dim3(N_TOK * HID / 8 / 256), blk, 0, stream>>>(
        attn, partA, partB, mbuf, lbuf, P);

    mfma_gemm<true><<<dim3(N_TOK / 128, OUT_DIM / 64), blk, 0, stream>>>(
        attn, fc0_w, fc0_b, (float*)d_out, HID, OUT_DIM);
}

// Round 6
// 294.237 us; speedup vs baseline: 10.2130x; 1.2045x over previous
//
#include <hip/hip_runtime.h>

#define N_TOK 8192
#define IN_DIM 512
#define HID 256
#define OUT_DIM 512

typedef _Float16 v8h __attribute__((ext_vector_type(8)));
typedef float v4f __attribute__((ext_vector_type(4)));

// async global->LDS, 16 B per lane. LDS dest must be wave-uniform base + lane*16.
__device__ inline void async_copy16(const void* g, void* l) {
    __builtin_amdgcn_global_load_lds(
        (const __attribute__((address_space(1))) void*)g,
        (__attribute__((address_space(3))) void*)l, 16, 0, 0);
}

// ---------- fused QKV projection ----------
// grid (64, 4, 3): z=0 -> qb, z=1 -> kb, z=2 -> vt (transposed write).
// C[8192 x 256] = O0[8192 x 512](f32->f16) @ Wz[256 x 512]^T + bz.
// BM=128 (4 waves x 32 rows), BN=64, BK=64.
__global__ __launch_bounds__(256)
void proj_qkv(const float* __restrict__ O0,
              const float* __restrict__ W_w, const float* __restrict__ W_b,
              const float* __restrict__ U_w, const float* __restrict__ U_b,
              const float* __restrict__ H_w, const float* __restrict__ H_b,
              _Float16* __restrict__ qb, _Float16* __restrict__ kb,
              _Float16* __restrict__ vt) {
    __shared__ _Float16 As[128][72];   // 144 B row stride = 9*16 (b128-aligned)
    __shared__ _Float16 Bs[64][72];

    const int t = threadIdx.x;
    const int wv = t >> 6;
    const int lane = t & 63;
    const int quad = lane >> 4;
    const int lm = lane & 15;
    const int m0 = blockIdx.x * 128;
    const int n0 = blockIdx.y * 64;
    const int z = blockIdx.z;

    const float* B    = (z == 0) ? W_w : (z == 1) ? U_w : H_w;
    const float* bias = (z == 0) ? W_b : (z == 1) ? U_b : H_b;

    v4f acc[2][4];
#pragma unroll
    for (int rs = 0; rs < 2; rs++)
#pragma unroll
        for (int ct = 0; ct < 4; ct++) acc[rs][ct] = (v4f){0.f, 0.f, 0.f, 0.f};

    for (int k0 = 0; k0 < IN_DIM; k0 += 64) {
        __syncthreads();
        // stage A: 128x64 fp32 -> f16; 2048 float4 slots, 8/thread
#pragma unroll
        for (int i = 0; i < 8; i++) {
            int slot = t + 256 * i;
            int ar = slot >> 4, ac4 = slot & 15;
            float4 f = *(const float4*)&O0[(size_t)(m0 + ar) * IN_DIM + k0 + ac4 * 4];
            union { _Float16 h[4]; uint2 u; } pk;
            pk.h[0] = (_Float16)f.x; pk.h[1] = (_Float16)f.y;
            pk.h[2] = (_Float16)f.z; pk.h[3] = (_Float16)f.w;
            *(uint2*)&As[ar][ac4 * 4] = pk.u;
        }
        // stage B: 64x64 fp32 -> f16; 1024 float4 slots, 4/thread
#pragma unroll
        for (int i = 0; i < 4; i++) {
            int slot = t + 256 * i;
            int br = slot >> 4, bc4 = slot & 15;
            float4 f = *(const float4*)&B[(size_t)(n0 + br) * IN_DIM + k0 + bc4 * 4];
            union { _Float16 h[4]; uint2 u; } pk;
            pk.h[0] = (_Float16)f.x; pk.h[1] = (_Float16)f.y;
            pk.h[2] = (_Float16)f.z; pk.h[3] = (_Float16)f.w;
            *(uint2*)&Bs[br][bc4 * 4] = pk.u;
        }
        __syncthreads();

#pragma unroll
        for (int kc = 0; kc < 2; kc++) {
            v8h a0 = *(const v8h*)&As[wv * 32 + lm][kc * 32 + quad * 8];
            v8h a1 = *(const v8h*)&As[wv * 32 + 16 + lm][kc * 32 + quad * 8];
            v8h b[4];
#pragma unroll
            for (int ct = 0; ct < 4; ct++)
                b[ct] = *(const v8h*)&Bs[ct * 16 + lm][kc * 32 + quad * 8];
#pragma unroll
            for (int ct = 0; ct < 4; ct++) {
                acc[0][ct] = __builtin_amdgcn_mfma_f32_16x16x32_f16(a0, b[ct], acc[0][ct], 0, 0, 0);
                acc[1][ct] = __builtin_amdgcn_mfma_f32_16x16x32_f16(a1, b[ct], acc[1][ct], 0, 0, 0);
            }
        }
    }

    if (z < 2) {
        _Float16* outp = (z == 0) ? qb : kb;
#pragma unroll
        for (int rs = 0; rs < 2; rs++)
#pragma unroll
            for (int ct = 0; ct < 4; ct++) {
                const int col = n0 + ct * 16 + lm;
                const float bv = bias[col];
#pragma unroll
                for (int r = 0; r < 4; r++) {
                    const int row = m0 + wv * 32 + rs * 16 + quad * 4 + r;
                    outp[(size_t)row * HID + col] = (_Float16)(acc[rs][ct][r] + bv);
                }
            }
    } else {
        // transposed write: vt[d][token], 4 consecutive tokens packed per store
#pragma unroll
        for (int rs = 0; rs < 2; rs++)
#pragma unroll
            for (int ct = 0; ct < 4; ct++) {
                const int col = n0 + ct * 16 + lm;     // d index
                const float bv = bias[col];
                const int rowbase = m0 + wv * 32 + rs * 16 + quad * 4;
                union { _Float16 h[4]; uint2 u; } pk;
#pragma unroll
                for (int r = 0; r < 4; r++) pk.h[r] = (_Float16)(acc[rs][ct][r] + bv);
                *(uint2*)&vt[(size_t)col * N_TOK + rowbase] = pk.u;
            }
    }
}

// ---------- MFMA flash attention, key-split, async double-buffered ----------
// Block: 256 thr = 4 waves x 32 Q-rows (BM=128). BN=32 keys/iter, D=256.
// LDS K/V unpadded with chunk-XOR swizzle (store chunk kc of row r at col
// (kc+r)&mask) -> wave-linear global_load_lds dest + <=2-way bank aliasing.
// ONE barrier per iter: loads for tile i+1 issue right after the barrier
// publishing tile i, overlapping tile-i compute.
__global__ __launch_bounds__(256, 2)
void flash_mfma(const _Float16* __restrict__ qb, const _Float16* __restrict__ kb,
                const _Float16* __restrict__ vt,
                _Float16* __restrict__ partA,   // parts 0..3 (d_out)
                _Float16* __restrict__ partB,   // parts 4..7 (ws)
                float* __restrict__ mbuf, float* __restrict__ lbuf,
                int keys_per_part) {
    __shared__ _Float16 Ks[2][32][256];   // swizzled: row kr, chunk kc at col (kc+kr)&31
    __shared__ _Float16 Vs[2][256][32];   // swizzled: row d, chunk c at col (c+d)&3
    __shared__ _Float16 Ps[4][32][40];    // per-wave P tile (VALU-written, padded)

    const int t = threadIdx.x;
    const int w = t >> 6;
    const int lane = t & 63;
    const int quad = lane >> 4;
    const int lm = lane & 15;
    const int p = blockIdx.y;
    const int m0 = blockIdx.x * 128 + w * 32;

    _Float16* part = (p < 4) ? partA + (size_t)p * N_TOK * HID
                             : partB + (size_t)(p - 4) * N_TOK * HID;

    // Q fragments held in registers (2 rowsets x 8 k-chunks)
    v8h aq[2][8];
#pragma unroll
    for (int rs = 0; rs < 2; rs++)
#pragma unroll
        for (int c = 0; c < 8; c++)
            aq[rs][c] = *(const v8h*)&qb[(size_t)(m0 + rs * 16 + lm) * HID + c * 32 + quad * 8];

    v4f o[2][16];
    float mr[2][4], lr[2][4];
#pragma unroll
    for (int rs = 0; rs < 2; rs++) {
#pragma unroll
        for (int dt = 0; dt < 16; dt++) o[rs][dt] = (v4f){0.f, 0.f, 0.f, 0.f};
#pragma unroll
        for (int r = 0; r < 4; r++) { mr[rs][r] = -1e30f; lr[rs][r] = 0.f; }
    }

    const int n_start = p * keys_per_part;
    const int iters = keys_per_part / 32;

    // async stage one 32-key K/V tile into LDS buffer `buf`
    auto issue = [&](int n0, int buf) {
#pragma unroll
        for (int i = 0; i < 4; i++) {
            int slot = t + 256 * i;
            {   // K: 1024 16B chunks; LDS dest linear in slot
                int kr = slot >> 5, cpos = slot & 31;
                int kcl = (cpos - kr) & 31;
                async_copy16(&kb[(size_t)(n0 + kr) * HID + kcl * 8],
                             (_Float16*)Ks[buf] + (size_t)slot * 8);
            }
            {   // V: 1024 16B chunks
                int d = slot >> 2, cpos = slot & 3;
                int ccl = (cpos - d) & 3;
                async_copy16(&vt[(size_t)d * N_TOK + n0 + ccl * 8],
                             (_Float16*)Vs[buf] + (size_t)slot * 8);
            }
        }
    };

    issue(n_start, 0);

    for (int it = 0; it < iters; it++) {
        const int buf = it & 1;
        __syncthreads();   // drains vmcnt -> buffer `buf` fully staged by all waves
        if (it + 1 < iters) issue(n_start + (it + 1) * 32, buf ^ 1);

        const _Float16* KsB = (const _Float16*)Ks[buf];
        const _Float16* VsB = (const _Float16*)Vs[buf];

        // QK^T: S[32 rows][32 keys] per wave
        v4f s[2][2];
#pragma unroll
        for (int rs = 0; rs < 2; rs++)
#pragma unroll
            for (int nt = 0; nt < 2; nt++) s[rs][nt] = (v4f){0.f, 0.f, 0.f, 0.f};
#pragma unroll
        for (int c = 0; c < 8; c++) {
            const int kc = c * 4 + quad;                  // logical chunk
            const int cp0 = (kc + lm) & 31;               // swizzled col, key row lm
            const int cp1 = (kc + 16 + lm) & 31;          // key row 16+lm
            v8h b0 = *(const v8h*)(KsB + lm * 256 + cp0 * 8);
            v8h b1 = *(const v8h*)(KsB + (16 + lm) * 256 + cp1 * 8);
            s[0][0] = __builtin_amdgcn_mfma_f32_16x16x32_f16(aq[0][c], b0, s[0][0], 0, 0, 0);
            s[0][1] = __builtin_amdgcn_mfma_f32_16x16x32_f16(aq[0][c], b1, s[0][1], 0, 0, 0);
            s[1][0] = __builtin_amdgcn_mfma_f32_16x16x32_f16(aq[1][c], b0, s[1][0], 0, 0, 0);
            s[1][1] = __builtin_amdgcn_mfma_f32_16x16x32_f16(aq[1][c], b1, s[1][1], 0, 0, 0);
        }

        // online softmax with wave-uniform rescale skip
#pragma unroll
        for (int rs = 0; rs < 2; rs++) {
            float mn[4];
            bool chg = false;
#pragma unroll
            for (int r = 0; r < 4; r++) {
                float tm = fmaxf(s[rs][0][r], s[rs][1][r]);
#pragma unroll
                for (int d = 1; d < 16; d <<= 1) tm = fmaxf(tm, __shfl_xor(tm, d));
                mn[r] = fmaxf(mr[rs][r], tm);
                chg = chg || (mn[r] > mr[rs][r]);
            }
            if (__any((int)chg)) {
                float al[4];
#pragma unroll
                for (int r = 0; r < 4; r++) {
                    al[r] = __expf(mr[rs][r] - mn[r]);
                    lr[rs][r] *= al[r];
                }
#pragma unroll
                for (int dt = 0; dt < 16; dt++)
#pragma unroll
                    for (int r = 0; r < 4; r++) o[rs][dt][r] *= al[r];
            }
#pragma unroll
            for (int r = 0; r < 4; r++) {
                mr[rs][r] = mn[r];
                float p0 = __expf(s[rs][0][r] - mn[r]);
                float p1v = __expf(s[rs][1][r] - mn[r]);
                float sm = p0 + p1v;
#pragma unroll
                for (int d = 1; d < 16; d <<= 1) sm += __shfl_xor(sm, d);
                lr[rs][r] += sm;
                const int prow = rs * 16 + quad * 4 + r;
                Ps[w][prow][lm] = (_Float16)p0;
                Ps[w][prow][16 + lm] = (_Float16)p1v;
            }
        }

        // PV (own-wave P slice; in-wave LDS ordering via lgkmcnt)
        v8h ap0 = *(const v8h*)&Ps[w][lm][quad * 8];
        v8h ap1 = *(const v8h*)&Ps[w][16 + lm][quad * 8];
#pragma unroll
        for (int dt = 0; dt < 16; dt++) {
            const int d0 = dt * 16 + lm;
            const int cp = (quad + d0) & 3;               // swizzled col
            v8h bv = *(const v8h*)(VsB + d0 * 32 + cp * 8);
            o[0][dt] = __builtin_amdgcn_mfma_f32_16x16x32_f16(ap0, bv, o[0][dt], 0, 0, 0);
            o[1][dt] = __builtin_amdgcn_mfma_f32_16x16x32_f16(ap1, bv, o[1][dt], 0, 0, 0);
        }
    }

    // store normalized partial (f16) + m, l
#pragma unroll
    for (int rs = 0; rs < 2; rs++) {
        float inv[4];
#pragma unroll
        for (int r = 0; r < 4; r++) inv[r] = 1.0f / lr[rs][r];
#pragma unroll
        for (int dt = 0; dt < 16; dt++)
#pragma unroll
            for (int r = 0; r < 4; r++)
                part[(size_t)(m0 + rs * 16 + quad * 4 + r) * HID + dt * 16 + lm] =
                    (_Float16)(o[rs][dt][r] * inv[r]);
        if (lm == 0) {
#pragma unroll
            for (int r = 0; r < 4; r++) {
                int row = m0 + rs * 16 + quad * 4 + r;
                mbuf[p * N_TOK + row] = mr[rs][r];
                lbuf[p * N_TOK + row] = lr[rs][r];
            }
        }
    }
}

// ---------- combine normalized partials -> attn f16 ----------
__global__ __launch_bounds__(256)
void combine_parts(_Float16* __restrict__ attn,
                   const _Float16* __restrict__ partA, const _Float16* __restrict__ partB,
                   const float* __restrict__ mbuf, const float* __restrict__ lbuf,
                   int P) {
    const int gid = blockIdx.x * 256 + threadIdx.x;  // 8-elem chunk
    const int row = gid >> 5;
    const int c8 = (gid & 31) * 8;

    float M = -1e30f;
    for (int p = 0; p < P; p++) M = fmaxf(M, mbuf[p * N_TOK + row]);
    float den = 0.f;
    float acc[8];
#pragma unroll
    for (int j = 0; j < 8; j++) acc[j] = 0.f;
    for (int p = 0; p < P; p++) {
        float wgt = lbuf[p * N_TOK + row] * __expf(mbuf[p * N_TOK + row] - M);
        den += wgt;
        const _Float16* base = (p < 4) ? partA + (size_t)p * N_TOK * HID
                                       : partB + (size_t)(p - 4) * N_TOK * HID;
        v8h y = *(const v8h*)&base[(size_t)row * HID + c8];
#pragma unroll
        for (int j = 0; j < 8; j++) acc[j] += wgt * (float)y[j];
    }
    const float inv = 1.0f / den;
    union { _Float16 h[8]; uint4 u; } pk;
#pragma unroll
    for (int j = 0; j < 8; j++) pk.h[j] = (_Float16)(acc[j] * inv);
    *(uint4*)&attn[(size_t)row * HID + c8] = pk.u;
}

// ---------- fc0: C[8192 x 512] = attn[8192 x 256](f16) @ fc0_w[512 x 256]^T + b ----------
__global__ __launch_bounds__(256)
void mfma_fc0(const _Float16* __restrict__ Ah, const float* __restrict__ B,
              const float* __restrict__ bias, float* __restrict__ Cout,
              int K, int NC) {
    __shared__ _Float16 As[128][72];
    __shared__ _Float16 Bs[64][72];

    const int t = threadIdx.x;
    const int wv = t >> 6;
    const int lane = t & 63;
    const int quad = lane >> 4;
    const int lm = lane & 15;
    const int m0 = blockIdx.x * 128;
    const int n0 = blockIdx.y * 64;

    v4f acc[2][4];
#pragma unroll
    for (int rs = 0; rs < 2; rs++)
#pragma unroll
        for (int ct = 0; ct < 4; ct++) acc[rs][ct] = (v4f){0.f, 0.f, 0.f, 0.f};

    for (int k0 = 0; k0 < K; k0 += 64) {
        __syncthreads();
        // stage A: 128x64 f16 = 1024 uint4, 4/thread
#pragma unroll
        for (int i = 0; i < 4; i++) {
            int slot = t + 256 * i;
            int ar = slot >> 3, ac8 = slot & 7;
            *(uint4*)&As[ar][ac8 * 8] =
                *(const uint4*)&Ah[(size_t)(m0 + ar) * K + k0 + ac8 * 8];
        }
        // stage B: 64x64 f32 -> f16
#pragma unroll
        for (int i = 0; i < 4; i++) {
            int slot = t + 256 * i;
            int br = slot >> 4, bc4 = slot & 15;
            float4 f = *(const float4*)&B[(size_t)(n0 + br) * K + k0 + bc4 * 4];
            union { _Float16 h[4]; uint2 u; } pk;
            pk.h[0] = (_Float16)f.x; pk.h[1] = (_Float16)f.y;
            pk.h[2] = (_Float16)f.z; pk.h[3] = (_Float16)f.w;
            *(uint2*)&Bs[br][bc4 * 4] = pk.u;
        }
        __syncthreads();

#pragma unroll
        for (int kc = 0; kc < 2; kc++) {
            v8h a0 = *(const v8h*)&As[wv * 32 + lm][kc * 32 + quad * 8];
            v8h a1 = *(const v8h*)&As[wv * 32 + 16 + lm][kc * 32 + quad * 8];
            v8h b[4];
#pragma unroll
            for (int ct = 0; ct < 4; ct++)
                b[ct] = *(const v8h*)&Bs[ct * 16 + lm][kc * 32 + quad * 8];
#pragma unroll
            for (int ct = 0; ct < 4; ct++) {
                acc[0][ct] = __builtin_amdgcn_mfma_f32_16x16x32_f16(a0, b[ct], acc[0][ct], 0, 0, 0);
                acc[1][ct] = __builtin_amdgcn_mfma_f32_16x16x32_f16(a1, b[ct], acc[1][ct], 0, 0, 0);
            }
        }
    }

#pragma unroll
    for (int rs = 0; rs < 2; rs++)
#pragma unroll
        for (int ct = 0; ct < 4; ct++) {
            const int col = n0 + ct * 16 + lm;
            const float bv = bias[col];
#pragma unroll
            for (int r = 0; r < 4; r++) {
                const int row = m0 + wv * 32 + rs * 16 + quad * 4 + r;
                Cout[(size_t)row * NC + col] = acc[rs][ct][r] + bv;
            }
        }
}

extern "C" void kernel_launch(void* const* d_in, const int* in_sizes, int n_in,
                              void* d_out, int out_size, void* d_ws, size_t ws_size,
                              hipStream_t stream) {
    const float* O0    = (const float*)d_in[0];
    const float* W_w   = (const float*)d_in[1];
    const float* W_b   = (const float*)d_in[2];
    const float* U_w   = (const float*)d_in[3];
    const float* U_b   = (const float*)d_in[4];
    const float* H_w   = (const float*)d_in[5];
    const float* H_b   = (const float*)d_in[6];
    const float* fc0_w = (const float*)d_in[7];
    const float* fc0_b = (const float*)d_in[8];

    // ws layout (MB): 0-4 qb (-> attn after flash), 4-8 kb, 8-12 vt,
    // 12-12.5 mbuf+lbuf, 16-32 parts 4..7 f16.
    // d_out: parts 0..3 (16 MB) -> overwritten by final fc0 output.
    char* ws = (char*)d_ws;
    _Float16* qb    = (_Float16*)ws;
    _Float16* kb    = (_Float16*)(ws + ((size_t)4 << 20));
    _Float16* vt    = (_Float16*)(ws + ((size_t)8 << 20));
    float*    mbuf  = (float*)(ws + ((size_t)12 << 20));
    float*    lbuf  = mbuf + 8 * N_TOK;
    _Float16* partB = (_Float16*)(ws + ((size_t)16 << 20));
    _Float16* attn  = qb;
    _Float16* partA = (_Float16*)d_out;

    const int P = (ws_size >= ((size_t)32 << 20)) ? 8 : 4;  // ws-size constant -> graph-safe
    const int kpp = N_TOK / P;

    dim3 blk(256);
    proj_qkv<<<dim3(N_TOK / 128, HID / 64, 3), blk, 0, stream>>>(
        O0, W_w, W_b, U_w, U_b, H_w, H_b, qb, kb, vt);

    flash_mfma<<<dim3(N_TOK / 128, P), blk, 0, stream>>>(
        qb, kb, vt, partA, partB, mbuf, lbuf, kpp);

    combine_parts<<<dim3(N_TOK * HID / 8 / 256), blk, 0, stream>>>(
        attn, partA, partB, mbuf, lbuf, P);

    mfma_fc0<<<dim3(N_TOK / 128, OUT_DIM / 64), blk, 0, stream>>>(
        attn, fc0_w, fc0_b, (float*)d_out, HID, OUT_DIM);
}

// Round 7
// 254.081 us; speedup vs baseline: 11.8271x; 1.1580x over previous
//
#include <hip/hip_runtime.h>

#define N_TOK 8192
#define IN_DIM 512
#define HID 256
#define OUT_DIM 512

typedef _Float16 v8h __attribute__((ext_vector_type(8)));
typedef float v4f __attribute__((ext_vector_type(4)));

// async global->LDS, 16 B per lane. LDS dest must be wave-uniform base + lane*16.
__device__ inline void async_copy16(const void* g, void* l) {
    __builtin_amdgcn_global_load_lds(
        (const __attribute__((address_space(1))) void*)g,
        (__attribute__((address_space(3))) void*)l, 16, 0, 0);
}

// DPP cross-lane move within 16-lane rows (VALU pipe, no LDS traffic)
template <int CTRL>
__device__ inline float dpp_mv(float x) {
    union { float f; int i; } a, b;
    a.f = x;
    b.i = __builtin_amdgcn_update_dpp(a.i, a.i, CTRL, 0xF, 0xF, false);
    return b.f;
}
// max over each 16-lane row: xor1, xor2 via quad_perm; 8/16 via mirrors
// (mirror pairings are valid butterflies for commutative reductions)
__device__ inline float rowmax16(float x) {
    x = fmaxf(x, dpp_mv<0xB1>(x));    // quad_perm [1,0,3,2]
    x = fmaxf(x, dpp_mv<0x4E>(x));    // quad_perm [2,3,0,1]
    x = fmaxf(x, dpp_mv<0x141>(x));   // row_half_mirror
    x = fmaxf(x, dpp_mv<0x140>(x));   // row_mirror
    return x;
}

// ---------- fused QKV projection ----------
// grid (64, 4, 3): z=0 -> qb, z=1 -> kb, z=2 -> vt (transposed write).
__global__ __launch_bounds__(256)
void proj_qkv(const float* __restrict__ O0,
              const float* __restrict__ W_w, const float* __restrict__ W_b,
              const float* __restrict__ U_w, const float* __restrict__ U_b,
              const float* __restrict__ H_w, const float* __restrict__ H_b,
              _Float16* __restrict__ qb, _Float16* __restrict__ kb,
              _Float16* __restrict__ vt) {
    __shared__ _Float16 As[128][72];   // 144 B row stride = 9*16 (b128-aligned)
    __shared__ _Float16 Bs[64][72];

    const int t = threadIdx.x;
    const int wv = t >> 6;
    const int lane = t & 63;
    const int quad = lane >> 4;
    const int lm = lane & 15;
    const int m0 = blockIdx.x * 128;
    const int n0 = blockIdx.y * 64;
    const int z = blockIdx.z;

    const float* B    = (z == 0) ? W_w : (z == 1) ? U_w : H_w;
    const float* bias = (z == 0) ? W_b : (z == 1) ? U_b : H_b;

    v4f acc[2][4];
#pragma unroll
    for (int rs = 0; rs < 2; rs++)
#pragma unroll
        for (int ct = 0; ct < 4; ct++) acc[rs][ct] = (v4f){0.f, 0.f, 0.f, 0.f};

    for (int k0 = 0; k0 < IN_DIM; k0 += 64) {
        __syncthreads();
#pragma unroll
        for (int i = 0; i < 8; i++) {
            int slot = t + 256 * i;
            int ar = slot >> 4, ac4 = slot & 15;
            float4 f = *(const float4*)&O0[(size_t)(m0 + ar) * IN_DIM + k0 + ac4 * 4];
            union { _Float16 h[4]; uint2 u; } pk;
            pk.h[0] = (_Float16)f.x; pk.h[1] = (_Float16)f.y;
            pk.h[2] = (_Float16)f.z; pk.h[3] = (_Float16)f.w;
            *(uint2*)&As[ar][ac4 * 4] = pk.u;
        }
#pragma unroll
        for (int i = 0; i < 4; i++) {
            int slot = t + 256 * i;
            int br = slot >> 4, bc4 = slot & 15;
            float4 f = *(const float4*)&B[(size_t)(n0 + br) * IN_DIM + k0 + bc4 * 4];
            union { _Float16 h[4]; uint2 u; } pk;
            pk.h[0] = (_Float16)f.x; pk.h[1] = (_Float16)f.y;
            pk.h[2] = (_Float16)f.z; pk.h[3] = (_Float16)f.w;
            *(uint2*)&Bs[br][bc4 * 4] = pk.u;
        }
        __syncthreads();

#pragma unroll
        for (int kc = 0; kc < 2; kc++) {
            v8h a0 = *(const v8h*)&As[wv * 32 + lm][kc * 32 + quad * 8];
            v8h a1 = *(const v8h*)&As[wv * 32 + 16 + lm][kc * 32 + quad * 8];
            v8h b[4];
#pragma unroll
            for (int ct = 0; ct < 4; ct++)
                b[ct] = *(const v8h*)&Bs[ct * 16 + lm][kc * 32 + quad * 8];
#pragma unroll
            for (int ct = 0; ct < 4; ct++) {
                acc[0][ct] = __builtin_amdgcn_mfma_f32_16x16x32_f16(a0, b[ct], acc[0][ct], 0, 0, 0);
                acc[1][ct] = __builtin_amdgcn_mfma_f32_16x16x32_f16(a1, b[ct], acc[1][ct], 0, 0, 0);
            }
        }
    }

    if (z < 2) {
        _Float16* outp = (z == 0) ? qb : kb;
#pragma unroll
        for (int rs = 0; rs < 2; rs++)
#pragma unroll
            for (int ct = 0; ct < 4; ct++) {
                const int col = n0 + ct * 16 + lm;
                const float bv = bias[col];
#pragma unroll
                for (int r = 0; r < 4; r++) {
                    const int row = m0 + wv * 32 + rs * 16 + quad * 4 + r;
                    outp[(size_t)row * HID + col] = (_Float16)(acc[rs][ct][r] + bv);
                }
            }
    } else {
#pragma unroll
        for (int rs = 0; rs < 2; rs++)
#pragma unroll
            for (int ct = 0; ct < 4; ct++) {
                const int col = n0 + ct * 16 + lm;     // d index
                const float bv = bias[col];
                const int rowbase = m0 + wv * 32 + rs * 16 + quad * 4;
                union { _Float16 h[4]; uint2 u; } pk;
#pragma unroll
                for (int r = 0; r < 4; r++) pk.h[r] = (_Float16)(acc[rs][ct][r] + bv);
                *(uint2*)&vt[(size_t)col * N_TOK + rowbase] = pk.u;
            }
    }
}

// ---------- MFMA flash attention, key-split, async double-buffered ----------
// 1-D grid of 512: p = id & 7 (XCD affinity: round-robin dispatch keeps one
// partition's 1 MB K/V slice per XCD L2), row-block = id >> 3.
// l tracked via ones-MFMA channel (no shuffle sums); row max via DPP.
__global__ __launch_bounds__(256, 2)
void flash_mfma(const _Float16* __restrict__ qb, const _Float16* __restrict__ kb,
                const _Float16* __restrict__ vt,
                _Float16* __restrict__ partA,   // parts 0..3 (d_out)
                _Float16* __restrict__ partB,   // parts 4..7 (ws)
                float* __restrict__ mbuf, float* __restrict__ lbuf,
                int keys_per_part) {
    __shared__ _Float16 Ks[2][32][256];   // swizzled: row kr, chunk kc at col (kc+kr)&31
    __shared__ _Float16 Vs[2][256][32];   // swizzled: row d, chunk c at col (c+d)&3
    __shared__ _Float16 Ps[4][32][40];    // per-wave P tile (VALU-written, padded)

    const int t = threadIdx.x;
    const int w = t >> 6;
    const int lane = t & 63;
    const int quad = lane >> 4;
    const int lm = lane & 15;
    const int p = blockIdx.x & 7;
    const int m0 = (blockIdx.x >> 3) * 128 + w * 32;

    _Float16* part = (p < 4) ? partA + (size_t)p * N_TOK * HID
                             : partB + (size_t)(p - 4) * N_TOK * HID;

    v8h aq[2][8];
#pragma unroll
    for (int rs = 0; rs < 2; rs++)
#pragma unroll
        for (int c = 0; c < 8; c++)
            aq[rs][c] = *(const v8h*)&qb[(size_t)(m0 + rs * 16 + lm) * HID + c * 32 + quad * 8];

    v8h vone;
#pragma unroll
    for (int j = 0; j < 8; j++) vone[j] = (_Float16)1.0f;

    v4f o[2][16];
    v4f lacc[2];
    float mr[2][4];
#pragma unroll
    for (int rs = 0; rs < 2; rs++) {
#pragma unroll
        for (int dt = 0; dt < 16; dt++) o[rs][dt] = (v4f){0.f, 0.f, 0.f, 0.f};
        lacc[rs] = (v4f){0.f, 0.f, 0.f, 0.f};
#pragma unroll
        for (int r = 0; r < 4; r++) mr[rs][r] = -1e30f;
    }

    const int n_start = p * keys_per_part;
    const int iters = keys_per_part / 32;

    auto issue = [&](int n0, int buf) {
#pragma unroll
        for (int i = 0; i < 4; i++) {
            int slot = t + 256 * i;
            {   // K: 1024 16B chunks; LDS dest linear in slot
                int kr = slot >> 5, cpos = slot & 31;
                int kcl = (cpos - kr) & 31;
                async_copy16(&kb[(size_t)(n0 + kr) * HID + kcl * 8],
                             (_Float16*)Ks[buf] + (size_t)slot * 8);
            }
            {   // V: 1024 16B chunks
                int d = slot >> 2, cpos = slot & 3;
                int ccl = (cpos - d) & 3;
                async_copy16(&vt[(size_t)d * N_TOK + n0 + ccl * 8],
                             (_Float16*)Vs[buf] + (size_t)slot * 8);
            }
        }
    };

    issue(n_start, 0);

    for (int it = 0; it < iters; it++) {
        const int buf = it & 1;
        __syncthreads();   // drains vmcnt -> buffer `buf` fully staged by all waves
        if (it + 1 < iters) issue(n_start + (it + 1) * 32, buf ^ 1);

        const _Float16* KsB = (const _Float16*)Ks[buf];
        const _Float16* VsB = (const _Float16*)Vs[buf];

        // QK^T
        v4f s[2][2];
#pragma unroll
        for (int rs = 0; rs < 2; rs++)
#pragma unroll
            for (int nt = 0; nt < 2; nt++) s[rs][nt] = (v4f){0.f, 0.f, 0.f, 0.f};
#pragma unroll
        for (int c = 0; c < 8; c++) {
            const int kc = c * 4 + quad;
            const int cp0 = (kc + lm) & 31;
            const int cp1 = (kc + 16 + lm) & 31;
            v8h b0 = *(const v8h*)(KsB + lm * 256 + cp0 * 8);
            v8h b1 = *(const v8h*)(KsB + (16 + lm) * 256 + cp1 * 8);
            s[0][0] = __builtin_amdgcn_mfma_f32_16x16x32_f16(aq[0][c], b0, s[0][0], 0, 0, 0);
            s[0][1] = __builtin_amdgcn_mfma_f32_16x16x32_f16(aq[0][c], b1, s[0][1], 0, 0, 0);
            s[1][0] = __builtin_amdgcn_mfma_f32_16x16x32_f16(aq[1][c], b0, s[1][0], 0, 0, 0);
            s[1][1] = __builtin_amdgcn_mfma_f32_16x16x32_f16(aq[1][c], b1, s[1][1], 0, 0, 0);
        }

        // online softmax: DPP row max; l handled by ones-MFMA channel
#pragma unroll
        for (int rs = 0; rs < 2; rs++) {
            float mn[4];
            bool chg = false;
#pragma unroll
            for (int r = 0; r < 4; r++) {
                float tm = rowmax16(fmaxf(s[rs][0][r], s[rs][1][r]));
                mn[r] = fmaxf(mr[rs][r], tm);
                chg = chg || (mn[r] > mr[rs][r]);
            }
            if (__any((int)chg)) {
                float al[4];
#pragma unroll
                for (int r = 0; r < 4; r++) {
                    al[r] = __expf(mr[rs][r] - mn[r]);
                    lacc[rs][r] *= al[r];
                }
#pragma unroll
                for (int dt = 0; dt < 16; dt++)
#pragma unroll
                    for (int r = 0; r < 4; r++) o[rs][dt][r] *= al[r];
            }
#pragma unroll
            for (int r = 0; r < 4; r++) {
                mr[rs][r] = mn[r];
                const int prow = rs * 16 + quad * 4 + r;
                Ps[w][prow][lm]      = (_Float16)__expf(s[rs][0][r] - mn[r]);
                Ps[w][prow][16 + lm] = (_Float16)__expf(s[rs][1][r] - mn[r]);
            }
        }

        // PV + ones-channel (l) — own-wave P slice, in-wave ordering via lgkmcnt
        v8h ap0 = *(const v8h*)&Ps[w][lm][quad * 8];
        v8h ap1 = *(const v8h*)&Ps[w][16 + lm][quad * 8];
        lacc[0] = __builtin_amdgcn_mfma_f32_16x16x32_f16(ap0, vone, lacc[0], 0, 0, 0);
        lacc[1] = __builtin_amdgcn_mfma_f32_16x16x32_f16(ap1, vone, lacc[1], 0, 0, 0);
#pragma unroll
        for (int dt = 0; dt < 16; dt++) {
            const int d0 = dt * 16 + lm;
            const int cp = (quad + d0) & 3;
            v8h bv = *(const v8h*)(VsB + d0 * 32 + cp * 8);
            o[0][dt] = __builtin_amdgcn_mfma_f32_16x16x32_f16(ap0, bv, o[0][dt], 0, 0, 0);
            o[1][dt] = __builtin_amdgcn_mfma_f32_16x16x32_f16(ap1, bv, o[1][dt], 0, 0, 0);
        }
    }

    // store normalized partial (f16) + m, l
#pragma unroll
    for (int rs = 0; rs < 2; rs++) {
        float inv[4];
#pragma unroll
        for (int r = 0; r < 4; r++) inv[r] = 1.0f / lacc[rs][r];
#pragma unroll
        for (int dt = 0; dt < 16; dt++)
#pragma unroll
            for (int r = 0; r < 4; r++)
                part[(size_t)(m0 + rs * 16 + quad * 4 + r) * HID + dt * 16 + lm] =
                    (_Float16)(o[rs][dt][r] * inv[r]);
        if (lm == 0) {
#pragma unroll
            for (int r = 0; r < 4; r++) {
                int row = m0 + rs * 16 + quad * 4 + r;
                mbuf[p * N_TOK + row] = mr[rs][r];
                lbuf[p * N_TOK + row] = lacc[rs][r];
            }
        }
    }
}

// ---------- combine normalized partials -> attn f16 ----------
__global__ __launch_bounds__(256)
void combine_parts(_Float16* __restrict__ attn,
                   const _Float16* __restrict__ partA, const _Float16* __restrict__ partB,
                   const float* __restrict__ mbuf, const float* __restrict__ lbuf,
                   int P) {
    const int gid = blockIdx.x * 256 + threadIdx.x;  // 8-elem chunk
    const int row = gid >> 5;
    const int c8 = (gid & 31) * 8;

    float M = -1e30f;
    for (int p = 0; p < P; p++) M = fmaxf(M, mbuf[p * N_TOK + row]);
    float den = 0.f;
    float acc[8];
#pragma unroll
    for (int j = 0; j < 8; j++) acc[j] = 0.f;
    for (int p = 0; p < P; p++) {
        float wgt = lbuf[p * N_TOK + row] * __expf(mbuf[p * N_TOK + row] - M);
        den += wgt;
        const _Float16* base = (p < 4) ? partA + (size_t)p * N_TOK * HID
                                       : partB + (size_t)(p - 4) * N_TOK * HID;
        v8h y = *(const v8h*)&base[(size_t)row * HID + c8];
#pragma unroll
        for (int j = 0; j < 8; j++) acc[j] += wgt * (float)y[j];
    }
    const float inv = 1.0f / den;
    union { _Float16 h[8]; uint4 u; } pk;
#pragma unroll
    for (int j = 0; j < 8; j++) pk.h[j] = (_Float16)(acc[j] * inv);
    *(uint4*)&attn[(size_t)row * HID + c8] = pk.u;
}

// ---------- fc0: C[8192 x 512] = attn[8192 x 256](f16) @ fc0_w[512 x 256]^T + b ----------
__global__ __launch_bounds__(256)
void mfma_fc0(const _Float16* __restrict__ Ah, const float* __restrict__ B,
              const float* __restrict__ bias, float* __restrict__ Cout,
              int K, int NC) {
    __shared__ _Float16 As[128][72];
    __shared__ _Float16 Bs[64][72];

    const int t = threadIdx.x;
    const int wv = t >> 6;
    const int lane = t & 63;
    const int quad = lane >> 4;
    const int lm = lane & 15;
    const int m0 = blockIdx.x * 128;
    const int n0 = blockIdx.y * 64;

    v4f acc[2][4];
#pragma unroll
    for (int rs = 0; rs < 2; rs++)
#pragma unroll
        for (int ct = 0; ct < 4; ct++) acc[rs][ct] = (v4f){0.f, 0.f, 0.f, 0.f};

    for (int k0 = 0; k0 < K; k0 += 64) {
        __syncthreads();
#pragma unroll
        for (int i = 0; i < 4; i++) {
            int slot = t + 256 * i;
            int ar = slot >> 3, ac8 = slot & 7;
            *(uint4*)&As[ar][ac8 * 8] =
                *(const uint4*)&Ah[(size_t)(m0 + ar) * K + k0 + ac8 * 8];
        }
#pragma unroll
        for (int i = 0; i < 4; i++) {
            int slot = t + 256 * i;
            int br = slot >> 4, bc4 = slot & 15;
            float4 f = *(const float4*)&B[(size_t)(n0 + br) * K + k0 + bc4 * 4];
            union { _Float16 h[4]; uint2 u; } pk;
            pk.h[0] = (_Float16)f.x; pk.h[1] = (_Float16)f.y;
            pk.h[2] = (_Float16)f.z; pk.h[3] = (_Float16)f.w;
            *(uint2*)&Bs[br][bc4 * 4] = pk.u;
        }
        __syncthreads();

#pragma unroll
        for (int kc = 0; kc < 2; kc++) {
            v8h a0 = *(const v8h*)&As[wv * 32 + lm][kc * 32 + quad * 8];
            v8h a1 = *(const v8h*)&As[wv * 32 + 16 + lm][kc * 32 + quad * 8];
            v8h b[4];
#pragma unroll
            for (int ct = 0; ct < 4; ct++)
                b[ct] = *(const v8h*)&Bs[ct * 16 + lm][kc * 32 + quad * 8];
#pragma unroll
            for (int ct = 0; ct < 4; ct++) {
                acc[0][ct] = __builtin_amdgcn_mfma_f32_16x16x32_f16(a0, b[ct], acc[0][ct], 0, 0, 0);
                acc[1][ct] = __builtin_amdgcn_mfma_f32_16x16x32_f16(a1, b[ct], acc[1][ct], 0, 0, 0);
            }
        }
    }

#pragma unroll
    for (int rs = 0; rs < 2; rs++)
#pragma unroll
        for (int ct = 0; ct < 4; ct++) {
            const int col = n0 + ct * 16 + lm;
            const float bv = bias[col];
#pragma unroll
            for (int r = 0; r < 4; r++) {
                const int row = m0 + wv * 32 + rs * 16 + quad * 4 + r;
                Cout[(size_t)row * NC + col] = acc[rs][ct][r] + bv;
            }
        }
}

extern "C" void kernel_launch(void* const* d_in, const int* in_sizes, int n_in,
                              void* d_out, int out_size, void* d_ws, size_t ws_size,
                              hipStream_t stream) {
    const float* O0    = (const float*)d_in[0];
    const float* W_w   = (const float*)d_in[1];
    const float* W_b   = (const float*)d_in[2];
    const float* U_w   = (const float*)d_in[3];
    const float* U_b   = (const float*)d_in[4];
    const float* H_w   = (const float*)d_in[5];
    const float* H_b   = (const float*)d_in[6];
    const float* fc0_w = (const float*)d_in[7];
    const float* fc0_b = (const float*)d_in[8];

    // ws layout (MB): 0-4 qb (-> attn after flash), 4-8 kb, 8-12 vt,
    // 12-12.5 mbuf+lbuf, 16-32 parts 4..7 f16.
    // d_out: parts 0..3 (16 MB) -> overwritten by final fc0 output.
    char* ws = (char*)d_ws;
    _Float16* qb    = (_Float16*)ws;
    _Float16* kb    = (_Float16*)(ws + ((size_t)4 << 20));
    _Float16* vt    = (_Float16*)(ws + ((size_t)8 << 20));
    float*    mbuf  = (float*)(ws + ((size_t)12 << 20));
    float*    lbuf  = mbuf + 8 * N_TOK;
    _Float16* partB = (_Float16*)(ws + ((size_t)16 << 20));
    _Float16* attn  = qb;
    _Float16* partA = (_Float16*)d_out;

    const int P = 8;
    const int kpp = N_TOK / P;

    dim3 blk(256);
    proj_qkv<<<dim3(N_TOK / 128, HID / 64, 3), blk, 0, stream>>>(
        O0, W_w, W_b, U_w, U_b, H_w, H_b, qb, kb, vt);

    flash_mfma<<<dim3((N_TOK / 128) * P), blk, 0, stream>>>(
        qb, kb, vt, partA, partB, mbuf, lbuf, kpp);

    combine_parts<<<dim3(N_TOK * HID / 8 / 256), blk, 0, stream>>>(
        attn, partA, partB, mbuf, lbuf, P);

    mfma_fc0<<<dim3(N_TOK / 128, OUT_DIM / 64), blk, 0, stream>>>(
        attn, fc0_w, fc0_b, (float*)d_out, HID, OUT_DIM);
}

// Round 8
// 218.267 us; speedup vs baseline: 13.7678x; 1.1641x over previous
//
#include <hip/hip_runtime.h>

#define N_TOK 8192
#define IN_DIM 512
#define HID 256
#define OUT_DIM 512

typedef _Float16 v8h __attribute__((ext_vector_type(8)));
typedef float v4f __attribute__((ext_vector_type(4)));

// async global->LDS, 16 B per lane. LDS dest must be wave-uniform base + lane*16.
__device__ inline void async_copy16(const void* g, void* l) {
    __builtin_amdgcn_global_load_lds(
        (const __attribute__((address_space(1))) void*)g,
        (__attribute__((address_space(3))) void*)l, 16, 0, 0);
}

// ---------- convert fp32 -> f16, 8 elems/thread ----------
__global__ __launch_bounds__(256)
void conv_f16(const float* __restrict__ in, _Float16* __restrict__ out) {
    const size_t i = ((size_t)blockIdx.x * 256 + threadIdx.x) * 8;
    float4 f0 = *(const float4*)&in[i];
    float4 f1 = *(const float4*)&in[i + 4];
    union { _Float16 h[8]; uint4 u; } pk;
    pk.h[0] = (_Float16)f0.x; pk.h[1] = (_Float16)f0.y;
    pk.h[2] = (_Float16)f0.z; pk.h[3] = (_Float16)f0.w;
    pk.h[4] = (_Float16)f1.x; pk.h[5] = (_Float16)f1.y;
    pk.h[6] = (_Float16)f1.z; pk.h[7] = (_Float16)f1.w;
    *(uint4*)&out[i] = pk.u;
}

// ---------- fused QKV projection ----------
// grid (64, 4, 3): z=0 -> qb, z=1 -> kb, z=2 -> vt (transposed write).
// A = O0h (pre-converted f16) staged as raw uint4 (no per-iter converts).
__global__ __launch_bounds__(256)
void proj_qkv(const _Float16* __restrict__ O0h,
              const float* __restrict__ W_w, const float* __restrict__ W_b,
              const float* __restrict__ U_w, const float* __restrict__ U_b,
              const float* __restrict__ H_w, const float* __restrict__ H_b,
              _Float16* __restrict__ qb, _Float16* __restrict__ kb,
              _Float16* __restrict__ vt) {
    __shared__ _Float16 As[128][72];   // 144 B row stride = 9*16 (b128-aligned)
    __shared__ _Float16 Bs[64][72];

    const int t = threadIdx.x;
    const int wv = t >> 6;
    const int lane = t & 63;
    const int quad = lane >> 4;
    const int lm = lane & 15;
    const int m0 = blockIdx.x * 128;
    const int n0 = blockIdx.y * 64;
    const int z = blockIdx.z;

    const float* B    = (z == 0) ? W_w : (z == 1) ? U_w : H_w;
    const float* bias = (z == 0) ? W_b : (z == 1) ? U_b : H_b;

    v4f acc[2][4];
#pragma unroll
    for (int rs = 0; rs < 2; rs++)
#pragma unroll
        for (int ct = 0; ct < 4; ct++) acc[rs][ct] = (v4f){0.f, 0.f, 0.f, 0.f};

    for (int k0 = 0; k0 < IN_DIM; k0 += 64) {
        __syncthreads();
        // stage A: 128x64 f16 = 1024 uint4, 4/thread
#pragma unroll
        for (int i = 0; i < 4; i++) {
            int slot = t + 256 * i;
            int ar = slot >> 3, ac8 = slot & 7;
            *(uint4*)&As[ar][ac8 * 8] =
                *(const uint4*)&O0h[(size_t)(m0 + ar) * IN_DIM + k0 + ac8 * 8];
        }
        // stage B: 64x64 fp32 -> f16; 1024 float4 slots, 4/thread
#pragma unroll
        for (int i = 0; i < 4; i++) {
            int slot = t + 256 * i;
            int br = slot >> 4, bc4 = slot & 15;
            float4 f = *(const float4*)&B[(size_t)(n0 + br) * IN_DIM + k0 + bc4 * 4];
            union { _Float16 h[4]; uint2 u; } pk;
            pk.h[0] = (_Float16)f.x; pk.h[1] = (_Float16)f.y;
            pk.h[2] = (_Float16)f.z; pk.h[3] = (_Float16)f.w;
            *(uint2*)&Bs[br][bc4 * 4] = pk.u;
        }
        __syncthreads();

#pragma unroll
        for (int kc = 0; kc < 2; kc++) {
            v8h a0 = *(const v8h*)&As[wv * 32 + lm][kc * 32 + quad * 8];
            v8h a1 = *(const v8h*)&As[wv * 32 + 16 + lm][kc * 32 + quad * 8];
            v8h b[4];
#pragma unroll
            for (int ct = 0; ct < 4; ct++)
                b[ct] = *(const v8h*)&Bs[ct * 16 + lm][kc * 32 + quad * 8];
#pragma unroll
            for (int ct = 0; ct < 4; ct++) {
                acc[0][ct] = __builtin_amdgcn_mfma_f32_16x16x32_f16(a0, b[ct], acc[0][ct], 0, 0, 0);
                acc[1][ct] = __builtin_amdgcn_mfma_f32_16x16x32_f16(a1, b[ct], acc[1][ct], 0, 0, 0);
            }
        }
    }

    if (z < 2) {
        _Float16* outp = (z == 0) ? qb : kb;
#pragma unroll
        for (int rs = 0; rs < 2; rs++)
#pragma unroll
            for (int ct = 0; ct < 4; ct++) {
                const int col = n0 + ct * 16 + lm;
                const float bv = bias[col];
#pragma unroll
                for (int r = 0; r < 4; r++) {
                    const int row = m0 + wv * 32 + rs * 16 + quad * 4 + r;
                    outp[(size_t)row * HID + col] = (_Float16)(acc[rs][ct][r] + bv);
                }
            }
    } else {
#pragma unroll
        for (int rs = 0; rs < 2; rs++)
#pragma unroll
            for (int ct = 0; ct < 4; ct++) {
                const int col = n0 + ct * 16 + lm;     // d index
                const float bv = bias[col];
                const int rowbase = m0 + wv * 32 + rs * 16 + quad * 4;
                union { _Float16 h[4]; uint2 u; } pk;
#pragma unroll
                for (int r = 0; r < 4; r++) pk.h[r] = (_Float16)(acc[rs][ct][r] + bv);
                *(uint2*)&vt[(size_t)col * N_TOK + rowbase] = pk.u;
            }
    }
}

// ---------- MFMA flash attention: S^T formulation ----------
// QK^T computed arg-swapped: S^T = mfma(K_frag, Q_frag) -> lane holds 8
// P-values of ONE q-row (lm), tokens 8*quad..8*quad+7 (via staged K-row
// permutation). P stays in registers as the PV B-operand; PV computes
// O^T = mfma(V^T_frag, P_frag). No P LDS round-trip.
// K single-buffered (staged after post-QK^T barrier), V double-buffered.
// LDS 48 KB. 1-D grid 512: p = id & 7 (XCD affinity).
__global__ __launch_bounds__(256, 2)
void flash_mfma(const _Float16* __restrict__ qb, const _Float16* __restrict__ kb,
                const _Float16* __restrict__ vt,
                _Float16* __restrict__ partA,   // parts 0..3 (d_out)
                _Float16* __restrict__ partB,   // parts 4..7 (ws)
                float* __restrict__ mbuf, float* __restrict__ lbuf,
                int keys_per_part) {
    __shared__ _Float16 Ks[32][256];      // chunk-xor swizzled, permuted rows
    __shared__ _Float16 Vs[2][256][32];   // linear: Vs[b][d][key]

    const int t = threadIdx.x;
    const int w = t >> 6;
    const int lane = t & 63;
    const int quad = lane >> 4;
    const int lm = lane & 15;
    const int p = blockIdx.x & 7;
    const int m0 = (blockIdx.x >> 3) * 128 + w * 32;

    _Float16* part = (p < 4) ? partA + (size_t)p * N_TOK * HID
                             : partB + (size_t)(p - 4) * N_TOK * HID;

    // Q fragments (B-operand layout: lane lm = q-row, quad = k-chunk)
    v8h aq[2][8];
#pragma unroll
    for (int rs = 0; rs < 2; rs++)
#pragma unroll
        for (int c = 0; c < 8; c++)
            aq[rs][c] = *(const v8h*)&qb[(size_t)(m0 + rs * 16 + lm) * HID + c * 32 + quad * 8];

    v4f o[2][16];          // O^T accumulators: C[m=d (quad*4+r)][n=qrow lm]
    float mr[2], lr[2];    // per-lane scalars: q-row = m0 + rs*16 + lm
#pragma unroll
    for (int rs = 0; rs < 2; rs++) {
#pragma unroll
        for (int dt = 0; dt < 16; dt++) o[rs][dt] = (v4f){0.f, 0.f, 0.f, 0.f};
        mr[rs] = -1e30f; lr[rs] = 0.f;
    }

    const int n_start = p * keys_per_part;
    const int iters = keys_per_part / 32;

    // K: LDS row m holds token n0 + 8*(m&15>>2) + (m>>4)*4 + (m&3), chunk-xor
    // swizzled so reads spread banks. 1024 16B chunks, 4/thread.
    auto issue_K = [&](int n0) {
#pragma unroll
        for (int i = 0; i < 4; i++) {
            int slot = t + 256 * i;
            int kr = slot >> 5, cpos = slot & 31;
            int kc = (cpos - kr) & 31;
            int m = kr & 15;
            int src = ((m >> 2) << 3) + ((kr >> 4) << 2) + (m & 3);
            async_copy16(&kb[(size_t)(n0 + src) * HID + kc * 8],
                         (_Float16*)Ks + (size_t)slot * 8);
        }
    };
    // V: identity layout Vs[b][d][key]. 1024 16B chunks, 4/thread.
    auto issue_V = [&](int n0, int b) {
#pragma unroll
        for (int i = 0; i < 4; i++) {
            int slot = t + 256 * i;
            int d = slot >> 2, c = slot & 3;
            async_copy16(&vt[(size_t)d * N_TOK + n0 + c * 8],
                         (_Float16*)Vs[b] + (size_t)slot * 8);
        }
    };

    issue_V(n_start, 0);
    issue_K(n_start);

    for (int it = 0; it < iters; it++) {
        __syncthreads();   // A: drains vmcnt -> K(it) and V(it) staged

        // QK^T -> S^T: C rows = keys (tokens 8q+r tile0 / 8q+4+r tile1), cols = q-rows
        v4f s[2][2];
#pragma unroll
        for (int rs = 0; rs < 2; rs++)
#pragma unroll
            for (int nt = 0; nt < 2; nt++) s[rs][nt] = (v4f){0.f, 0.f, 0.f, 0.f};
#pragma unroll
        for (int c = 0; c < 8; c++) {
            const int kc = c * 4 + quad;
            const int cp0 = (kc + lm) & 31;
            const int cp1 = (kc + 16 + lm) & 31;
            v8h b0 = *(const v8h*)((const _Float16*)Ks + lm * 256 + cp0 * 8);
            v8h b1 = *(const v8h*)((const _Float16*)Ks + (16 + lm) * 256 + cp1 * 8);
            s[0][0] = __builtin_amdgcn_mfma_f32_16x16x32_f16(b0, aq[0][c], s[0][0], 0, 0, 0);
            s[0][1] = __builtin_amdgcn_mfma_f32_16x16x32_f16(b1, aq[0][c], s[0][1], 0, 0, 0);
            s[1][0] = __builtin_amdgcn_mfma_f32_16x16x32_f16(b0, aq[1][c], s[1][0], 0, 0, 0);
            s[1][1] = __builtin_amdgcn_mfma_f32_16x16x32_f16(b1, aq[1][c], s[1][1], 0, 0, 0);
        }

        __syncthreads();   // B: all waves done reading Ks (nothing outstanding -> cheap)
        if (it + 1 < iters) {
            issue_K(n_start + (it + 1) * 32);
            issue_V(n_start + (it + 1) * 32, (it + 1) & 1);
        }

        // softmax in registers: per-lane scalar m/l for q-row lm
        v8h bp[2];
#pragma unroll
        for (int rs = 0; rs < 2; rs++) {
            float tm = s[rs][0][0];
#pragma unroll
            for (int r = 1; r < 4; r++) tm = fmaxf(tm, s[rs][0][r]);
#pragma unroll
            for (int r = 0; r < 4; r++) tm = fmaxf(tm, s[rs][1][r]);
            tm = fmaxf(tm, __shfl_xor(tm, 16));
            tm = fmaxf(tm, __shfl_xor(tm, 32));
            float mn = fmaxf(mr[rs], tm);
            if (__any((int)(mn > mr[rs]))) {
                float al = __expf(mr[rs] - mn);
                lr[rs] *= al;
#pragma unroll
                for (int dt = 0; dt < 16; dt++)
#pragma unroll
                    for (int r = 0; r < 4; r++) o[rs][dt][r] *= al;
            }
            mr[rs] = mn;
            float ls = 0.f;
            v8h bpv;
#pragma unroll
            for (int j = 0; j < 4; j++) {
                float p0 = __expf(s[rs][0][j] - mn);
                float p1 = __expf(s[rs][1][j] - mn);
                bpv[j] = (_Float16)p0;
                bpv[j + 4] = (_Float16)p1;
                ls += p0 + p1;
            }
            ls += __shfl_xor(ls, 16);
            ls += __shfl_xor(ls, 32);
            lr[rs] += ls;
            bp[rs] = bpv;
        }

        // PV: O^T += V^T_frag (A) * P_frag (B); av reused for both rowsets
        const _Float16* VsB = (const _Float16*)Vs[it & 1];
#pragma unroll
        for (int dt = 0; dt < 16; dt++) {
            v8h av = *(const v8h*)(VsB + (dt * 16 + lm) * 32 + quad * 8);
            o[0][dt] = __builtin_amdgcn_mfma_f32_16x16x32_f16(av, bp[0], o[0][dt], 0, 0, 0);
            o[1][dt] = __builtin_amdgcn_mfma_f32_16x16x32_f16(av, bp[1], o[1][dt], 0, 0, 0);
        }
    }

    // store normalized partial (f16, packed uint2) + m, l
#pragma unroll
    for (int rs = 0; rs < 2; rs++) {
        const float inv = 1.0f / lr[rs];
        const int row = m0 + rs * 16 + lm;
#pragma unroll
        for (int dt = 0; dt < 16; dt++) {
            union { _Float16 h[4]; uint2 u; } pk;
#pragma unroll
            for (int r = 0; r < 4; r++) pk.h[r] = (_Float16)(o[rs][dt][r] * inv);
            *(uint2*)&part[(size_t)row * HID + dt * 16 + quad * 4] = pk.u;
        }
        if (quad == 0) {
            mbuf[p * N_TOK + row] = mr[rs];
            lbuf[p * N_TOK + row] = lr[rs];
        }
    }
}

// ---------- combine normalized partials -> attn f16 ----------
__global__ __launch_bounds__(256)
void combine_parts(_Float16* __restrict__ attn,
                   const _Float16* __restrict__ partA, const _Float16* __restrict__ partB,
                   const float* __restrict__ mbuf, const float* __restrict__ lbuf,
                   int P) {
    const int gid = blockIdx.x * 256 + threadIdx.x;  // 8-elem chunk
    const int row = gid >> 5;
    const int c8 = (gid & 31) * 8;

    float M = -1e30f;
    for (int p = 0; p < P; p++) M = fmaxf(M, mbuf[p * N_TOK + row]);
    float den = 0.f;
    float acc[8];
#pragma unroll
    for (int j = 0; j < 8; j++) acc[j] = 0.f;
    for (int p = 0; p < P; p++) {
        float wgt = lbuf[p * N_TOK + row] * __expf(mbuf[p * N_TOK + row] - M);
        den += wgt;
        const _Float16* base = (p < 4) ? partA + (size_t)p * N_TOK * HID
                                       : partB + (size_t)(p - 4) * N_TOK * HID;
        v8h y = *(const v8h*)&base[(size_t)row * HID + c8];
#pragma unroll
        for (int j = 0; j < 8; j++) acc[j] += wgt * (float)y[j];
    }
    const float inv = 1.0f / den;
    union { _Float16 h[8]; uint4 u; } pk;
#pragma unroll
    for (int j = 0; j < 8; j++) pk.h[j] = (_Float16)(acc[j] * inv);
    *(uint4*)&attn[(size_t)row * HID + c8] = pk.u;
}

// ---------- fc0: C[8192 x 512] = attn[8192 x 256](f16) @ fc0_w[512 x 256]^T + b ----------
__global__ __launch_bounds__(256)
void mfma_fc0(const _Float16* __restrict__ Ah, const float* __restrict__ B,
              const float* __restrict__ bias, float* __restrict__ Cout,
              int K, int NC) {
    __shared__ _Float16 As[128][72];
    __shared__ _Float16 Bs[64][72];

    const int t = threadIdx.x;
    const int wv = t >> 6;
    const int lane = t & 63;
    const int quad = lane >> 4;
    const int lm = lane & 15;
    const int m0 = blockIdx.x * 128;
    const int n0 = blockIdx.y * 64;

    v4f acc[2][4];
#pragma unroll
    for (int rs = 0; rs < 2; rs++)
#pragma unroll
        for (int ct = 0; ct < 4; ct++) acc[rs][ct] = (v4f){0.f, 0.f, 0.f, 0.f};

    for (int k0 = 0; k0 < K; k0 += 64) {
        __syncthreads();
#pragma unroll
        for (int i = 0; i < 4; i++) {
            int slot = t + 256 * i;
            int ar = slot >> 3, ac8 = slot & 7;
            *(uint4*)&As[ar][ac8 * 8] =
                *(const uint4*)&Ah[(size_t)(m0 + ar) * K + k0 + ac8 * 8];
        }
#pragma unroll
        for (int i = 0; i < 4; i++) {
            int slot = t + 256 * i;
            int br = slot >> 4, bc4 = slot & 15;
            float4 f = *(const float4*)&B[(size_t)(n0 + br) * K + k0 + bc4 * 4];
            union { _Float16 h[4]; uint2 u; } pk;
            pk.h[0] = (_Float16)f.x; pk.h[1] = (_Float16)f.y;
            pk.h[2] = (_Float16)f.z; pk.h[3] = (_Float16)f.w;
            *(uint2*)&Bs[br][bc4 * 4] = pk.u;
        }
        __syncthreads();

#pragma unroll
        for (int kc = 0; kc < 2; kc++) {
            v8h a0 = *(const v8h*)&As[wv * 32 + lm][kc * 32 + quad * 8];
            v8h a1 = *(const v8h*)&As[wv * 32 + 16 + lm][kc * 32 + quad * 8];
            v8h b[4];
#pragma unroll
            for (int ct = 0; ct < 4; ct++)
                b[ct] = *(const v8h*)&Bs[ct * 16 + lm][kc * 32 + quad * 8];
#pragma unroll
            for (int ct = 0; ct < 4; ct++) {
                acc[0][ct] = __builtin_amdgcn_mfma_f32_16x16x32_f16(a0, b[ct], acc[0][ct], 0, 0, 0);
                acc[1][ct] = __builtin_amdgcn_mfma_f32_16x16x32_f16(a1, b[ct], acc[1][ct], 0, 0, 0);
            }
        }
    }

#pragma unroll
    for (int rs = 0; rs < 2; rs++)
#pragma unroll
        for (int ct = 0; ct < 4; ct++) {
            const int col = n0 + ct * 16 + lm;
            const float bv = bias[col];
#pragma unroll
            for (int r = 0; r < 4; r++) {
                const int row = m0 + wv * 32 + rs * 16 + quad * 4 + r;
                Cout[(size_t)row * NC + col] = acc[rs][ct][r] + bv;
            }
        }
}

extern "C" void kernel_launch(void* const* d_in, const int* in_sizes, int n_in,
                              void* d_out, int out_size, void* d_ws, size_t ws_size,
                              hipStream_t stream) {
    const float* O0    = (const float*)d_in[0];
    const float* W_w   = (const float*)d_in[1];
    const float* W_b   = (const float*)d_in[2];
    const float* U_w   = (const float*)d_in[3];
    const float* U_b   = (const float*)d_in[4];
    const float* H_w   = (const float*)d_in[5];
    const float* H_b   = (const float*)d_in[6];
    const float* fc0_w = (const float*)d_in[7];
    const float* fc0_b = (const float*)d_in[8];

    // ws layout (MB): 0-4 qb (-> attn after flash), 4-8 kb, 8-12 vt,
    // 12-12.5 mbuf+lbuf, 16-32 parts 4..7 f16.
    // d_out: O0h f16 (8 MB, dead after proj) -> parts 0..3 (16 MB) -> final.
    char* ws = (char*)d_ws;
    _Float16* qb    = (_Float16*)ws;
    _Float16* kb    = (_Float16*)(ws + ((size_t)4 << 20));
    _Float16* vt    = (_Float16*)(ws + ((size_t)8 << 20));
    float*    mbuf  = (float*)(ws + ((size_t)12 << 20));
    float*    lbuf  = mbuf + 8 * N_TOK;
    _Float16* partB = (_Float16*)(ws + ((size_t)16 << 20));
    _Float16* attn  = qb;
    _Float16* O0h   = (_Float16*)d_out;   // dead before partials are written
    _Float16* partA = (_Float16*)d_out;

    const int P = 8;
    const int kpp = N_TOK / P;

    dim3 blk(256);
    conv_f16<<<dim3(N_TOK * IN_DIM / 8 / 256), blk, 0, stream>>>(O0, O0h);

    proj_qkv<<<dim3(N_TOK / 128, HID / 64, 3), blk, 0, stream>>>(
        O0h, W_w, W_b, U_w, U_b, H_w, H_b, qb, kb, vt);

    flash_mfma<<<dim3((N_TOK / 128) * P), blk, 0, stream>>>(
        qb, kb, vt, partA, partB, mbuf, lbuf, kpp);

    combine_parts<<<dim3(N_TOK * HID / 8 / 256), blk, 0, stream>>>(
        attn, partA, partB, mbuf, lbuf, P);

    mfma_fc0<<<dim3(N_TOK / 128, OUT_DIM / 64), blk, 0, stream>>>(
        attn, fc0_w, fc0_b, (float*)d_out, HID, OUT_DIM);
}